// Round 1
// baseline (1141.134 us; speedup 1.0000x reference)
//
#include <hip/hip_runtime.h>

#define K_NN 20
#define NEG_INF (-__builtin_inff())

constexpr int BB   = 16;
constexpr int NN   = 2048;
constexpr int CATC = 512;                 // concat feature width
constexpr int ROW_G = BB * NN;            // 32768 points total

// ---------------------------------------------------------------------------
// kNN stage 1: per (batch, row-tile 128, candidate-chunk 256) keep top-20 keys.
// key = sortable(d)<<11 | (2047-idx)  -> ordering == jax.top_k (val desc, idx asc)
// ---------------------------------------------------------------------------
__global__ __launch_bounds__(128) void knn_chunk_kernel(const float* __restrict__ x,
                                                        unsigned long long* __restrict__ ck) {
  __shared__ float mx[256], my[256], mz[256], msq[256];
  const int bid = blockIdx.x;
  const int ch = bid & 7;          // candidate chunk (8 x 256)
  const int rt = (bid >> 3) & 15;  // row tile (16 x 128)
  const int b  = bid >> 7;         // batch
  const float* xb = x + (size_t)b * NN * 3;

  for (int i = threadIdx.x; i < 256; i += 128) {
    const int m = ch * 256 + i;
    const float px = xb[m*3+0], py = xb[m*3+1], pz = xb[m*3+2];
    mx[i] = px; my[i] = py; mz[i] = pz;
    msq[i] = fmaf(pz, pz, fmaf(py, py, px*px));
  }
  __syncthreads();

  const int n = rt * 128 + threadIdx.x;
  const float cx = xb[n*3+0], cy = xb[n*3+1], cz = xb[n*3+2];
  const float csq = fmaf(cz, cz, fmaf(cy, cy, cx*cx));

  unsigned long long keys[K_NN];
#pragma unroll
  for (int j = 0; j < K_NN; ++j) keys[j] = 0ULL;  // below any real key

  for (int i = 0; i < 256; ++i) {
    const float inner = fmaf(cz, mz[i], fmaf(cy, my[i], cx*mx[i]));
    const float d = 2.0f * inner - csq - msq[i];   // same order as reference
    unsigned int ub = __float_as_uint(d);
    ub = (ub & 0x80000000u) ? ~ub : (ub | 0x80000000u);   // order-preserving map
    const unsigned long long key =
        ((unsigned long long)ub << 11) | (unsigned long long)(2047 - (ch*256 + i));
    if (key > keys[K_NN-1]) {                       // sorted-shift insert (desc)
#pragma unroll
      for (int j = K_NN-1; j >= 1; --j) {
        const bool sh = keys[j-1] < key;
        keys[j] = sh ? keys[j-1] : ((keys[j] < key) ? key : keys[j]);
      }
      if (keys[0] < key) keys[0] = key;
    }
  }

  const int rowg = b * NN + n;
#pragma unroll
  for (int j = 0; j < K_NN; ++j)                    // column layout -> coalesced
    ck[(size_t)(ch*K_NN + j) * ROW_G + rowg] = keys[j];
}

// ---------------------------------------------------------------------------
// kNN stage 2: merge 8 chunk lists (160 keys) -> final 20 indices per row
// ---------------------------------------------------------------------------
__global__ __launch_bounds__(256) void knn_merge_kernel(const unsigned long long* __restrict__ ck,
                                                        int* __restrict__ idx_out) {
  const int t = blockIdx.x * 256 + threadIdx.x;     // global row id
  unsigned long long keys[K_NN];
#pragma unroll
  for (int j = 0; j < K_NN; ++j) keys[j] = ck[(size_t)j * ROW_G + t];  // chunk0 (sorted)
  for (int i = K_NN; i < 8 * K_NN; ++i) {
    const unsigned long long key = ck[(size_t)i * ROW_G + t];
    if (key > keys[K_NN-1]) {
#pragma unroll
      for (int j = K_NN-1; j >= 1; --j) {
        const bool sh = keys[j-1] < key;
        keys[j] = sh ? keys[j-1] : ((keys[j] < key) ? key : keys[j]);
      }
      if (keys[0] < key) keys[0] = key;
    }
  }
  int* op = idx_out + (size_t)t * K_NN;
#pragma unroll
  for (int j = 0; j < K_NN; ++j) op[j] = 2047 - (int)(keys[j] & 2047ULL);
}

// ---------------------------------------------------------------------------
// EdgeConv: h = max_k act(W0 @ [x_nbr - x, x] + b0) -> cat cols [0,64)
// 64 lanes = 64 output channels, 4 points/block
// ---------------------------------------------------------------------------
__global__ __launch_bounds__(256) void edgeconv_kernel(const float* __restrict__ x,
    const int* __restrict__ idx, const float* __restrict__ W0,
    const float* __restrict__ b0, float* __restrict__ cat) {
  const int o  = threadIdx.x & 63;
  const int pt = blockIdx.x * 4 + (threadIdx.x >> 6);
  const int b  = pt >> 11, n = pt & (NN - 1);
  const float* xb = x + (size_t)b * NN * 3;

  const float w0 = W0[o*6+0], w1 = W0[o*6+1], w2 = W0[o*6+2];
  const float w3 = W0[o*6+3], w4 = W0[o*6+4], w5 = W0[o*6+5];
  const float bias = b0[o];
  const float cx = xb[n*3+0], cy = xb[n*3+1], cz = xb[n*3+2];

  const int* ip = idx + (size_t)pt * K_NN;
  float px = 0.f, py = 0.f, pz = 0.f;
  if (o < K_NN) { const int m = ip[o]; px = xb[m*3+0]; py = xb[m*3+1]; pz = xb[m*3+2]; }

  float best = NEG_INF;
#pragma unroll
  for (int k = 0; k < K_NN; ++k) {
    const float ax = __shfl(px, k, 64), ay = __shfl(py, k, 64), az = __shfl(pz, k, 64);
    float h = w0 * (ax - cx);
    h = fmaf(w1, ay - cy, h);
    h = fmaf(w2, az - cz, h);
    h = fmaf(w3, cx, h);
    h = fmaf(w4, cy, h);
    h = fmaf(w5, cz, h);
    h += bias;
    h = (h > 0.f) ? h : 0.2f * h;
    best = fmaxf(best, h);
  }
  cat[(size_t)pt * CATC + o] = best;
}

// ---------------------------------------------------------------------------
// pool (max over fixed kNN graph) + 1x1 conv + leaky relu.
// Reads cat cols [coff_in, coff_in+CIN), writes [coff_out, coff_out+COUT).
// ---------------------------------------------------------------------------
template<int CIN, int COUT, int PTS>
__global__ __launch_bounds__(256) void pool_mlp_kernel(float* __restrict__ cat,
    const int* __restrict__ idx, const float* __restrict__ W,
    const float* __restrict__ bias, int coff_in, int coff_out) {
  __shared__ float pooled[PTS][CIN];
  __shared__ int sidx[PTS][K_NN];
  const int pt0 = blockIdx.x * PTS;

  for (int t = threadIdx.x; t < PTS * K_NN; t += 256)
    sidx[t / K_NN][t % K_NN] = idx[(size_t)pt0 * K_NN + t];
  __syncthreads();

  for (int t = threadIdx.x; t < PTS * CIN; t += 256) {
    const int p = t / CIN, c = t % CIN;
    const int bq = (pt0 + p) >> 11;
    const float* base = cat + (size_t)bq * NN * CATC + coff_in + c;
    float mv = NEG_INF;
#pragma unroll
    for (int k = 0; k < K_NN; ++k)
      mv = fmaxf(mv, base[(size_t)sidx[p][k] * CATC]);
    pooled[p][c] = mv;
  }
  __syncthreads();

  for (int t = threadIdx.x; t < PTS * COUT; t += 256) {
    const int p = t / COUT, o = t % COUT;
    const float4* pp = (const float4*)&pooled[p][0];
    const float4* wp = (const float4*)(W + (size_t)o * CIN);
    float acc = 0.f;
#pragma unroll
    for (int c4 = 0; c4 < CIN / 4; ++c4) {
      const float4 pv = pp[c4], wv = wp[c4];
      acc = fmaf(pv.x, wv.x, acc);
      acc = fmaf(pv.y, wv.y, acc);
      acc = fmaf(pv.z, wv.z, acc);
      acc = fmaf(pv.w, wv.w, acc);
    }
    float h = acc + bias[o];
    h = (h > 0.f) ? h : 0.2f * h;
    cat[(size_t)(pt0 + p) * CATC + coff_out + o] = h;
  }
}

// ---------------------------------------------------------------------------
// Final: out[b,o] = act(bf[o] + max_n cat[b,n,:] . Wf[o,:])
// 128x128 tile, 8x8 micro-tile, fp32 FMA, running max -> partials[b][chunk][1024]
// ---------------------------------------------------------------------------
__global__ __launch_bounds__(256) void final_gemm_kernel(const float* __restrict__ cat,
    const float* __restrict__ Wf, float* __restrict__ partials) {
  __shared__ float As[16][132];
  __shared__ float Ws[16][132];
  __shared__ float smax[16][128];
  const int ot = blockIdx.x;       // 8 output tiles of 128
  const int chunk = blockIdx.y;    // 16 row chunks of 128
  const int b = blockIdx.z;
  const int tid = threadIdx.x;
  const int trow = tid >> 4, tcol = tid & 15;
  const float* Abase = cat + ((size_t)b * NN + (size_t)chunk * 128) * CATC;
  const float* Wbase = Wf + (size_t)ot * 128 * CATC;

  float acc[8][8];
#pragma unroll
  for (int p = 0; p < 8; ++p)
#pragma unroll
    for (int q = 0; q < 8; ++q) acc[p][q] = 0.f;

  const int li = tid >> 2;        // 0..63
  const int lj = (tid & 3) * 4;   // 0,4,8,12
  for (int kt = 0; kt < 32; ++kt) {
    const int k0 = kt * 16;
    const float4 a0 = *(const float4*)(Abase + (size_t)li * CATC + k0 + lj);
    const float4 a1 = *(const float4*)(Abase + (size_t)(li + 64) * CATC + k0 + lj);
    const float4 w0 = *(const float4*)(Wbase + (size_t)li * CATC + k0 + lj);
    const float4 w1 = *(const float4*)(Wbase + (size_t)(li + 64) * CATC + k0 + lj);
    __syncthreads();  // previous iteration's LDS reads complete
    As[lj+0][li] = a0.x; As[lj+1][li] = a0.y; As[lj+2][li] = a0.z; As[lj+3][li] = a0.w;
    As[lj+0][li+64] = a1.x; As[lj+1][li+64] = a1.y; As[lj+2][li+64] = a1.z; As[lj+3][li+64] = a1.w;
    Ws[lj+0][li] = w0.x; Ws[lj+1][li] = w0.y; Ws[lj+2][li] = w0.z; Ws[lj+3][li] = w0.w;
    Ws[lj+0][li+64] = w1.x; Ws[lj+1][li+64] = w1.y; Ws[lj+2][li+64] = w1.z; Ws[lj+3][li+64] = w1.w;
    __syncthreads();
#pragma unroll
    for (int kk = 0; kk < 16; ++kk) {
      float a[8], w[8];
      *(float4*)&a[0] = *(const float4*)&As[kk][trow * 8];
      *(float4*)&a[4] = *(const float4*)&As[kk][trow * 8 + 4];
      *(float4*)&w[0] = *(const float4*)&Ws[kk][tcol * 8];
      *(float4*)&w[4] = *(const float4*)&Ws[kk][tcol * 8 + 4];
#pragma unroll
      for (int p = 0; p < 8; ++p)
#pragma unroll
        for (int q = 0; q < 8; ++q)
          acc[p][q] = fmaf(a[p], w[q], acc[p][q]);
    }
  }

  float cmax[8];
#pragma unroll
  for (int q = 0; q < 8; ++q) {
    float m = acc[0][q];
#pragma unroll
    for (int p = 1; p < 8; ++p) m = fmaxf(m, acc[p][q]);
    cmax[q] = m;
  }
  __syncthreads();
#pragma unroll
  for (int q = 0; q < 8; ++q) smax[trow][tcol * 8 + q] = cmax[q];
  __syncthreads();
  if (tid < 128) {
    float m = smax[0][tid];
#pragma unroll
    for (int r = 1; r < 16; ++r) m = fmaxf(m, smax[r][tid]);
    partials[((size_t)(b * 16 + chunk)) * 1024 + (size_t)ot * 128 + tid] = m;
  }
}

__global__ __launch_bounds__(256) void final_reduce_kernel(const float* __restrict__ partials,
    const float* __restrict__ bf, float* __restrict__ out) {
  const int t = blockIdx.x * 256 + threadIdx.x;   // 16384
  const int b = t >> 10, o = t & 1023;
  float m = NEG_INF;
#pragma unroll
  for (int c = 0; c < 16; ++c)
    m = fmaxf(m, partials[((size_t)(b * 16 + c)) * 1024 + o]);
  float h = m + bf[o];
  out[t] = (h > 0.f) ? h : 0.2f * h;   // act(max+b) == max(act(.+b)) (monotone)
}

// ---------------------------------------------------------------------------
extern "C" void kernel_launch(void* const* d_in, const int* in_sizes, int n_in,
                              void* d_out, int out_size, void* d_ws, size_t ws_size,
                              hipStream_t stream) {
  (void)in_sizes; (void)n_in; (void)out_size; (void)ws_size;
  const float* x  = (const float*)d_in[0];
  const float* W0 = (const float*)d_in[1];
  const float* b0 = (const float*)d_in[2];
  const float* W1 = (const float*)d_in[3];
  const float* b1 = (const float*)d_in[4];
  const float* W2 = (const float*)d_in[5];
  const float* b2 = (const float*)d_in[6];
  const float* W3 = (const float*)d_in[7];
  const float* b3 = (const float*)d_in[8];
  const float* Wf = (const float*)d_in[9];
  const float* bf = (const float*)d_in[10];
  float* out = (float*)d_out;

  // ws layout (bytes):
  //   [0, 2621440)                : idx (int, B*N*20)
  //   [2621440, 2621440+41.9MB)   : ck  (u64 keys, 160*32768) -- dead after merge
  //   [2621440, 2621440+67.1MB)   : cat (float, B*N*512)      -- aliases ck (safe: stream order)
  //   [69730304, +1MB)            : partials (float, 16*16*1024)
  char* ws = (char*)d_ws;
  int* idx_ws = (int*)ws;
  unsigned long long* ck = (unsigned long long*)(ws + 2621440);
  float* cat = (float*)(ws + 2621440);
  float* partials = (float*)(ws + 2621440 + 67108864);

  knn_chunk_kernel<<<BB * 16 * 8, 128, 0, stream>>>(x, ck);
  knn_merge_kernel<<<ROW_G / 256, 256, 0, stream>>>(ck, idx_ws);
  edgeconv_kernel<<<ROW_G / 4, 256, 0, stream>>>(x, idx_ws, W0, b0, cat);
  pool_mlp_kernel<64, 64, 16><<<ROW_G / 16, 256, 0, stream>>>(cat, idx_ws, W1, b1, 0, 64);
  pool_mlp_kernel<64, 128, 8><<<ROW_G / 8, 256, 0, stream>>>(cat, idx_ws, W2, b2, 64, 128);
  pool_mlp_kernel<128, 256, 8><<<ROW_G / 8, 256, 0, stream>>>(cat, idx_ws, W3, b3, 128, 256);
  final_gemm_kernel<<<dim3(8, 16, BB), 256, 0, stream>>>(cat, Wf, partials);
  final_reduce_kernel<<<BB * 1024 / 256, 256, 0, stream>>>(partials, bf, out);
}

// Round 3
// 1090.712 us; speedup vs baseline: 1.0462x; 1.0462x over previous
//
#include <hip/hip_runtime.h>

#define K_NN 20
#define NEG_INF (-__builtin_inff())

constexpr int BB   = 16;
constexpr int NN   = 2048;
constexpr int CATC = 512;                 // concat feature width
constexpr int ROW_G = BB * NN;            // 32768 points total

__device__ __forceinline__ unsigned long long umax64(unsigned long long a, unsigned long long b) {
  return a < b ? b : a;
}
__device__ __forceinline__ unsigned long long umin64(unsigned long long a, unsigned long long b) {
  return a < b ? a : b;
}

// Named-register sorted top-20 list (desc): k0 >= k1 >= ... >= k19.
// Insert = compare-select shift network; NO arrays -> no scratch (rule #20).
#define DECL_KEYS(INIT) \
  unsigned long long k0=INIT,k1=INIT,k2=INIT,k3=INIT,k4=INIT,k5=INIT,k6=INIT,k7=INIT, \
                     k8=INIT,k9=INIT,k10=INIT,k11=INIT,k12=INIT,k13=INIT,k14=INIT,    \
                     k15=INIT,k16=INIT,k17=INIT,k18=INIT,k19=INIT;

#define INSERT_KEY(key) do { if ((key) > k19) {            \
    k19 = umin64(k18, umax64(k19, (key)));                 \
    k18 = umin64(k17, umax64(k18, (key)));                 \
    k17 = umin64(k16, umax64(k17, (key)));                 \
    k16 = umin64(k15, umax64(k16, (key)));                 \
    k15 = umin64(k14, umax64(k15, (key)));                 \
    k14 = umin64(k13, umax64(k14, (key)));                 \
    k13 = umin64(k12, umax64(k13, (key)));                 \
    k12 = umin64(k11, umax64(k12, (key)));                 \
    k11 = umin64(k10, umax64(k11, (key)));                 \
    k10 = umin64(k9,  umax64(k10, (key)));                 \
    k9  = umin64(k8,  umax64(k9,  (key)));                 \
    k8  = umin64(k7,  umax64(k8,  (key)));                 \
    k7  = umin64(k6,  umax64(k7,  (key)));                 \
    k6  = umin64(k5,  umax64(k6,  (key)));                 \
    k5  = umin64(k4,  umax64(k5,  (key)));                 \
    k4  = umin64(k3,  umax64(k4,  (key)));                 \
    k3  = umin64(k2,  umax64(k3,  (key)));                 \
    k2  = umin64(k1,  umax64(k2,  (key)));                 \
    k1  = umin64(k0,  umax64(k1,  (key)));                 \
    k0  = umax64(k0, (key));                               \
  } } while (0)

// ---------------------------------------------------------------------------
// kNN stage 1: per (batch, row-tile 128, candidate-chunk 256) keep top-20 keys.
// key = sortable(d)<<11 | (2047-idx)  -> ordering == jax.top_k (val desc, idx asc)
// ---------------------------------------------------------------------------
__global__ __launch_bounds__(128) void knn_chunk_kernel(const float* __restrict__ x,
                                                        unsigned long long* __restrict__ ck) {
  __shared__ float4 cand[256];           // {x, y, z, sq} per candidate
  const int bid = blockIdx.x;
  const int ch = bid & 7;          // candidate chunk (8 x 256)
  const int rt = (bid >> 3) & 15;  // row tile (16 x 128)
  const int b  = bid >> 7;         // batch
  const float* xb = x + (size_t)b * NN * 3;

  for (int i = threadIdx.x; i < 256; i += 128) {
    const int m = ch * 256 + i;
    const float px = xb[m*3+0], py = xb[m*3+1], pz = xb[m*3+2];
    cand[i] = make_float4(px, py, pz, fmaf(pz, pz, fmaf(py, py, px*px)));
  }
  __syncthreads();

  const int n = rt * 128 + threadIdx.x;
  const float cx = xb[n*3+0], cy = xb[n*3+1], cz = xb[n*3+2];
  const float csq = fmaf(cz, cz, fmaf(cy, cy, cx*cx));

  DECL_KEYS(0ULL)

  for (int i = 0; i < 256; ++i) {
    const float4 c = cand[i];
    const float inner = fmaf(cz, c.z, fmaf(cy, c.y, cx*c.x));
    const float d = 2.0f * inner - csq - c.w;      // same order as reference
    unsigned int ub = __float_as_uint(d);
    ub = (ub & 0x80000000u) ? ~ub : (ub | 0x80000000u);   // order-preserving map
    const unsigned long long key =
        ((unsigned long long)ub << 11) | (unsigned long long)(2047 - (ch*256 + i));
    INSERT_KEY(key);
  }

  const int rowg = b * NN + n;
#define STORE_KEY(i) ck[(size_t)(ch*K_NN + i) * ROW_G + rowg] = k##i;
  STORE_KEY(0) STORE_KEY(1) STORE_KEY(2) STORE_KEY(3) STORE_KEY(4)
  STORE_KEY(5) STORE_KEY(6) STORE_KEY(7) STORE_KEY(8) STORE_KEY(9)
  STORE_KEY(10) STORE_KEY(11) STORE_KEY(12) STORE_KEY(13) STORE_KEY(14)
  STORE_KEY(15) STORE_KEY(16) STORE_KEY(17) STORE_KEY(18) STORE_KEY(19)
#undef STORE_KEY
}

// ---------------------------------------------------------------------------
// kNN stage 2: merge 8 chunk lists (160 keys) -> final 20 indices per row
// ---------------------------------------------------------------------------
__global__ __launch_bounds__(256) void knn_merge_kernel(const unsigned long long* __restrict__ ck,
                                                        int* __restrict__ idx_out) {
  const int t = blockIdx.x * 256 + threadIdx.x;     // global row id
  // chunk 0's list is already sorted desc -> direct init
#define LOAD_KEY(i) unsigned long long k##i = ck[(size_t)i * ROW_G + t];
  LOAD_KEY(0) LOAD_KEY(1) LOAD_KEY(2) LOAD_KEY(3) LOAD_KEY(4)
  LOAD_KEY(5) LOAD_KEY(6) LOAD_KEY(7) LOAD_KEY(8) LOAD_KEY(9)
  LOAD_KEY(10) LOAD_KEY(11) LOAD_KEY(12) LOAD_KEY(13) LOAD_KEY(14)
  LOAD_KEY(15) LOAD_KEY(16) LOAD_KEY(17) LOAD_KEY(18) LOAD_KEY(19)
#undef LOAD_KEY
  for (int i = K_NN; i < 8 * K_NN; ++i) {
    const unsigned long long key = ck[(size_t)i * ROW_G + t];
    INSERT_KEY(key);
  }
  int* op = idx_out + (size_t)t * K_NN;
#define OUT_KEY(i) op[i] = 2047 - (int)(k##i & 2047ULL);
  OUT_KEY(0) OUT_KEY(1) OUT_KEY(2) OUT_KEY(3) OUT_KEY(4)
  OUT_KEY(5) OUT_KEY(6) OUT_KEY(7) OUT_KEY(8) OUT_KEY(9)
  OUT_KEY(10) OUT_KEY(11) OUT_KEY(12) OUT_KEY(13) OUT_KEY(14)
  OUT_KEY(15) OUT_KEY(16) OUT_KEY(17) OUT_KEY(18) OUT_KEY(19)
#undef OUT_KEY
}

// ---------------------------------------------------------------------------
// EdgeConv: h = max_k act(W0 @ [x_nbr - x, x] + b0) -> cat cols [0,64)
// 64 lanes = 64 output channels, 4 points/block
// ---------------------------------------------------------------------------
__global__ __launch_bounds__(256) void edgeconv_kernel(const float* __restrict__ x,
    const int* __restrict__ idx, const float* __restrict__ W0,
    const float* __restrict__ b0, float* __restrict__ cat) {
  const int o  = threadIdx.x & 63;
  const int pt = blockIdx.x * 4 + (threadIdx.x >> 6);
  const int b  = pt >> 11, n = pt & (NN - 1);
  const float* xb = x + (size_t)b * NN * 3;

  const float w0 = W0[o*6+0], w1 = W0[o*6+1], w2 = W0[o*6+2];
  const float w3 = W0[o*6+3], w4 = W0[o*6+4], w5 = W0[o*6+5];
  const float bias = b0[o];
  const float cx = xb[n*3+0], cy = xb[n*3+1], cz = xb[n*3+2];

  const int* ip = idx + (size_t)pt * K_NN;
  float px = 0.f, py = 0.f, pz = 0.f;
  if (o < K_NN) { const int m = ip[o]; px = xb[m*3+0]; py = xb[m*3+1]; pz = xb[m*3+2]; }

  float best = NEG_INF;
#pragma unroll
  for (int k = 0; k < K_NN; ++k) {
    const float ax = __shfl(px, k, 64), ay = __shfl(py, k, 64), az = __shfl(pz, k, 64);
    float h = w0 * (ax - cx);
    h = fmaf(w1, ay - cy, h);
    h = fmaf(w2, az - cz, h);
    h = fmaf(w3, cx, h);
    h = fmaf(w4, cy, h);
    h = fmaf(w5, cz, h);
    h += bias;
    h = (h > 0.f) ? h : 0.2f * h;
    best = fmaxf(best, h);
  }
  cat[(size_t)pt * CATC + o] = best;
}

// ---------------------------------------------------------------------------
// pool (max over fixed kNN graph) + 1x1 conv + leaky relu.
// Reads cat cols [coff_in, coff_in+CIN), writes [coff_out, coff_out+COUT).
// ---------------------------------------------------------------------------
template<int CIN, int COUT, int PTS>
__global__ __launch_bounds__(256) void pool_mlp_kernel(float* __restrict__ cat,
    const int* __restrict__ idx, const float* __restrict__ W,
    const float* __restrict__ bias, int coff_in, int coff_out) {
  __shared__ float pooled[PTS][CIN];
  __shared__ int sidx[PTS][K_NN];
  const int pt0 = blockIdx.x * PTS;

  for (int t = threadIdx.x; t < PTS * K_NN; t += 256)
    sidx[t / K_NN][t % K_NN] = idx[(size_t)pt0 * K_NN + t];
  __syncthreads();

  for (int t = threadIdx.x; t < PTS * CIN; t += 256) {
    const int p = t / CIN, c = t % CIN;
    const int bq = (pt0 + p) >> 11;
    const float* base = cat + (size_t)bq * NN * CATC + coff_in + c;
    float mv = NEG_INF;
#pragma unroll
    for (int k = 0; k < K_NN; ++k)
      mv = fmaxf(mv, base[(size_t)sidx[p][k] * CATC]);
    pooled[p][c] = mv;
  }
  __syncthreads();

  for (int t = threadIdx.x; t < PTS * COUT; t += 256) {
    const int p = t / COUT, o = t % COUT;
    const float4* pp = (const float4*)&pooled[p][0];
    const float4* wp = (const float4*)(W + (size_t)o * CIN);
    float acc = 0.f;
#pragma unroll
    for (int c4 = 0; c4 < CIN / 4; ++c4) {
      const float4 pv = pp[c4], wv = wp[c4];
      acc = fmaf(pv.x, wv.x, acc);
      acc = fmaf(pv.y, wv.y, acc);
      acc = fmaf(pv.z, wv.z, acc);
      acc = fmaf(pv.w, wv.w, acc);
    }
    float h = acc + bias[o];
    h = (h > 0.f) ? h : 0.2f * h;
    cat[(size_t)(pt0 + p) * CATC + coff_out + o] = h;
  }
}

// ---------------------------------------------------------------------------
// Final: out[b,o] = act(bf[o] + max_n cat[b,n,:] . Wf[o,:])
// 128x128 tile, 8x8 micro-tile, fp32 FMA, running max -> partials[b][chunk][1024]
// ---------------------------------------------------------------------------
__global__ __launch_bounds__(256) void final_gemm_kernel(const float* __restrict__ cat,
    const float* __restrict__ Wf, float* __restrict__ partials) {
  __shared__ float As[16][132];
  __shared__ float Ws[16][132];
  __shared__ float smax[16][128];
  const int ot = blockIdx.x;       // 8 output tiles of 128
  const int chunk = blockIdx.y;    // 16 row chunks of 128
  const int b = blockIdx.z;
  const int tid = threadIdx.x;
  const int trow = tid >> 4, tcol = tid & 15;
  const float* Abase = cat + ((size_t)b * NN + (size_t)chunk * 128) * CATC;
  const float* Wbase = Wf + (size_t)ot * 128 * CATC;

  float acc[8][8];
#pragma unroll
  for (int p = 0; p < 8; ++p)
#pragma unroll
    for (int q = 0; q < 8; ++q) acc[p][q] = 0.f;

  const int li = tid >> 2;        // 0..63
  const int lj = (tid & 3) * 4;   // 0,4,8,12
  for (int kt = 0; kt < 32; ++kt) {
    const int k0 = kt * 16;
    const float4 a0 = *(const float4*)(Abase + (size_t)li * CATC + k0 + lj);
    const float4 a1 = *(const float4*)(Abase + (size_t)(li + 64) * CATC + k0 + lj);
    const float4 w0 = *(const float4*)(Wbase + (size_t)li * CATC + k0 + lj);
    const float4 w1 = *(const float4*)(Wbase + (size_t)(li + 64) * CATC + k0 + lj);
    __syncthreads();  // previous iteration's LDS reads complete
    As[lj+0][li] = a0.x; As[lj+1][li] = a0.y; As[lj+2][li] = a0.z; As[lj+3][li] = a0.w;
    As[lj+0][li+64] = a1.x; As[lj+1][li+64] = a1.y; As[lj+2][li+64] = a1.z; As[lj+3][li+64] = a1.w;
    Ws[lj+0][li] = w0.x; Ws[lj+1][li] = w0.y; Ws[lj+2][li] = w0.z; Ws[lj+3][li] = w0.w;
    Ws[lj+0][li+64] = w1.x; Ws[lj+1][li+64] = w1.y; Ws[lj+2][li+64] = w1.z; Ws[lj+3][li+64] = w1.w;
    __syncthreads();
#pragma unroll
    for (int kk = 0; kk < 16; ++kk) {
      float a[8], w[8];
      *(float4*)&a[0] = *(const float4*)&As[kk][trow * 8];
      *(float4*)&a[4] = *(const float4*)&As[kk][trow * 8 + 4];
      *(float4*)&w[0] = *(const float4*)&Ws[kk][tcol * 8];
      *(float4*)&w[4] = *(const float4*)&Ws[kk][tcol * 8 + 4];
#pragma unroll
      for (int p = 0; p < 8; ++p)
#pragma unroll
        for (int q = 0; q < 8; ++q)
          acc[p][q] = fmaf(a[p], w[q], acc[p][q]);
    }
  }

  float cmax[8];
#pragma unroll
  for (int q = 0; q < 8; ++q) {
    float m = acc[0][q];
#pragma unroll
    for (int p = 1; p < 8; ++p) m = fmaxf(m, acc[p][q]);
    cmax[q] = m;
  }
  __syncthreads();
#pragma unroll
  for (int q = 0; q < 8; ++q) smax[trow][tcol * 8 + q] = cmax[q];
  __syncthreads();
  if (tid < 128) {
    float m = smax[0][tid];
#pragma unroll
    for (int r = 1; r < 16; ++r) m = fmaxf(m, smax[r][tid]);
    partials[((size_t)(b * 16 + chunk)) * 1024 + (size_t)ot * 128 + tid] = m;
  }
}

__global__ __launch_bounds__(256) void final_reduce_kernel(const float* __restrict__ partials,
    const float* __restrict__ bf, float* __restrict__ out) {
  const int t = blockIdx.x * 256 + threadIdx.x;   // 16384
  const int b = t >> 10, o = t & 1023;
  float m = NEG_INF;
#pragma unroll
  for (int c = 0; c < 16; ++c)
    m = fmaxf(m, partials[((size_t)(b * 16 + c)) * 1024 + o]);
  float h = m + bf[o];
  out[t] = (h > 0.f) ? h : 0.2f * h;   // act(max+b) == max(act(.+b)) (monotone)
}

// ---------------------------------------------------------------------------
extern "C" void kernel_launch(void* const* d_in, const int* in_sizes, int n_in,
                              void* d_out, int out_size, void* d_ws, size_t ws_size,
                              hipStream_t stream) {
  (void)in_sizes; (void)n_in; (void)out_size; (void)ws_size;
  const float* x  = (const float*)d_in[0];
  const float* W0 = (const float*)d_in[1];
  const float* b0 = (const float*)d_in[2];
  const float* W1 = (const float*)d_in[3];
  const float* b1 = (const float*)d_in[4];
  const float* W2 = (const float*)d_in[5];
  const float* b2 = (const float*)d_in[6];
  const float* W3 = (const float*)d_in[7];
  const float* b3 = (const float*)d_in[8];
  const float* Wf = (const float*)d_in[9];
  const float* bf = (const float*)d_in[10];
  float* out = (float*)d_out;

  // ws layout (bytes):
  //   [0, 2621440)                : idx (int, B*N*20)
  //   [2621440, 2621440+41.9MB)   : ck  (u64 keys, 160*32768) -- dead after merge
  //   [2621440, 2621440+67.1MB)   : cat (float, B*N*512)      -- aliases ck (safe: stream order)
  //   [69730304, +1MB)            : partials (float, 16*16*1024)
  char* ws = (char*)d_ws;
  int* idx_ws = (int*)ws;
  unsigned long long* ck = (unsigned long long*)(ws + 2621440);
  float* cat = (float*)(ws + 2621440);
  float* partials = (float*)(ws + 2621440 + 67108864);

  knn_chunk_kernel<<<BB * 16 * 8, 128, 0, stream>>>(x, ck);
  knn_merge_kernel<<<ROW_G / 256, 256, 0, stream>>>(ck, idx_ws);
  edgeconv_kernel<<<ROW_G / 4, 256, 0, stream>>>(x, idx_ws, W0, b0, cat);
  pool_mlp_kernel<64, 64, 16><<<ROW_G / 16, 256, 0, stream>>>(cat, idx_ws, W1, b1, 0, 64);
  pool_mlp_kernel<64, 128, 8><<<ROW_G / 8, 256, 0, stream>>>(cat, idx_ws, W2, b2, 64, 128);
  pool_mlp_kernel<128, 256, 8><<<ROW_G / 8, 256, 0, stream>>>(cat, idx_ws, W3, b3, 128, 256);
  final_gemm_kernel<<<dim3(8, 16, BB), 256, 0, stream>>>(cat, Wf, partials);
  final_reduce_kernel<<<BB * 1024 / 256, 256, 0, stream>>>(partials, bf, out);
}

// Round 4
// 1032.649 us; speedup vs baseline: 1.1051x; 1.0562x over previous
//
#include <hip/hip_runtime.h>

#define K_NN 20
#define NEG_INF (-__builtin_inff())

constexpr int BB   = 16;
constexpr int NN   = 2048;
constexpr int CATC = 512;                 // concat feature width
constexpr int ROW_G = BB * NN;            // 32768 points total

// ---------------------------------------------------------------------------
// Branch-free u32 top-20 VALUE network (desc, duplicates kept).
// Native v_min_u32/v_max_u32 -> 2 instr/level, all values hot -> no spill.
// Level order v19..v0 so each v_{j-1} is read before being overwritten.
// ---------------------------------------------------------------------------
#define DECL_VALS(INIT) \
  unsigned int v0=INIT,v1=INIT,v2=INIT,v3=INIT,v4=INIT,v5=INIT,v6=INIT,v7=INIT, \
               v8=INIT,v9=INIT,v10=INIT,v11=INIT,v12=INIT,v13=INIT,v14=INIT,    \
               v15=INIT,v16=INIT,v17=INIT,v18=INIT,v19=INIT;

#define INSERT_VAL(x) do {                         \
    v19 = min(v18, max(v19, (x)));                 \
    v18 = min(v17, max(v18, (x)));                 \
    v17 = min(v16, max(v17, (x)));                 \
    v16 = min(v15, max(v16, (x)));                 \
    v15 = min(v14, max(v15, (x)));                 \
    v14 = min(v13, max(v14, (x)));                 \
    v13 = min(v12, max(v13, (x)));                 \
    v12 = min(v11, max(v12, (x)));                 \
    v11 = min(v10, max(v11, (x)));                 \
    v10 = min(v9,  max(v10, (x)));                 \
    v9  = min(v8,  max(v9,  (x)));                 \
    v8  = min(v7,  max(v8,  (x)));                 \
    v7  = min(v6,  max(v7,  (x)));                 \
    v6  = min(v5,  max(v6,  (x)));                 \
    v5  = min(v4,  max(v5,  (x)));                 \
    v4  = min(v3,  max(v4,  (x)));                 \
    v3  = min(v2,  max(v3,  (x)));                 \
    v2  = min(v1,  max(v2,  (x)));                 \
    v1  = min(v0,  max(v1,  (x)));                 \
    v0  = max(v0, (x));                            \
  } while (0)

// Order-preserving float->u32 map. Distances are <= 0.0f and never -0.0f
// (a-b with a==b yields +0.0), so all mapped values are in [0x00800000, 0x80000000].
__device__ __forceinline__ unsigned int sortable(float d) {
  unsigned int ub = __float_as_uint(d);
  return (ub & 0x80000000u) ? ~ub : (ub | 0x80000000u);
}

// ---------------------------------------------------------------------------
// kNN stage 1: per (batch, row-tile 128, candidate-chunk 256) keep the top-20
// DISTANCE VALUES (u32 sortable domain). No indices here.
// ---------------------------------------------------------------------------
__global__ __launch_bounds__(128) void knn_chunk_kernel(const float* __restrict__ x,
                                                        unsigned int* __restrict__ cv) {
  __shared__ float4 cand[256];           // {x, y, z, sq} per candidate
  const int bid = blockIdx.x;
  const int ch = bid & 7;          // candidate chunk (8 x 256)
  const int rt = (bid >> 3) & 15;  // row tile (16 x 128)
  const int b  = bid >> 7;         // batch
  const float* xb = x + (size_t)b * NN * 3;

  for (int i = threadIdx.x; i < 256; i += 128) {
    const int m = ch * 256 + i;
    const float px = xb[m*3+0], py = xb[m*3+1], pz = xb[m*3+2];
    cand[i] = make_float4(px, py, pz, fmaf(pz, pz, fmaf(py, py, px*px)));
  }
  __syncthreads();

  const int n = rt * 128 + threadIdx.x;
  const float cx = xb[n*3+0], cy = xb[n*3+1], cz = xb[n*3+2];
  const float csq = fmaf(cz, cz, fmaf(cy, cy, cx*cx));

  DECL_VALS(0u)   // 0 < any real mapped value

#pragma unroll 4
  for (int i = 0; i < 256; ++i) {
    const float4 c = cand[i];
    const float inner = fmaf(cz, c.z, fmaf(cy, c.y, cx*c.x));
    const float d = 2.0f * inner - csq - c.w;      // same op order as reference
    const unsigned int u = sortable(d);
    INSERT_VAL(u);                                  // unconditional: no spill, no divergence
  }

  const int rowg = b * NN + n;
#define STORE_VAL(i) cv[(size_t)(ch*K_NN + i) * ROW_G + rowg] = v##i;
  STORE_VAL(0) STORE_VAL(1) STORE_VAL(2) STORE_VAL(3) STORE_VAL(4)
  STORE_VAL(5) STORE_VAL(6) STORE_VAL(7) STORE_VAL(8) STORE_VAL(9)
  STORE_VAL(10) STORE_VAL(11) STORE_VAL(12) STORE_VAL(13) STORE_VAL(14)
  STORE_VAL(15) STORE_VAL(16) STORE_VAL(17) STORE_VAL(18) STORE_VAL(19)
#undef STORE_VAL
}

// ---------------------------------------------------------------------------
// kNN stage 2 (fused merge + index recovery). Per row:
//  1. merge 8 chunk value-lists (160 u32) -> d20 = 20th largest value
//  2. rescan all 2048 candidates (bit-identical distance):
//       dist > d20  -> member (provably <= 19 of them)
//       dist == d20 -> tie pool; take lowest indices (asc scan order) to fill 20
//  => exactly jax.lax.top_k's membership (value desc, index-asc ties).
//  Output order within the 20 is irrelevant: all consumers max-pool over the set.
// ---------------------------------------------------------------------------
__global__ __launch_bounds__(256) void knn_recover_kernel(const float* __restrict__ x,
                                                          const unsigned int* __restrict__ cv,
                                                          int* __restrict__ idx_out) {
  __shared__ float4 cand[NN];            // whole batch's candidates: 32 KB
  __shared__ unsigned short eq[256][K_NN];
  const int r = blockIdx.x * 256 + threadIdx.x;   // global row; block spans one batch
  const int b = r >> 11;
  const float* xb = x + (size_t)b * NN * 3;

  for (int i = threadIdx.x; i < NN; i += 256) {
    const float px = xb[i*3+0], py = xb[i*3+1], pz = xb[i*3+2];
    cand[i] = make_float4(px, py, pz, fmaf(pz, pz, fmaf(py, py, px*px)));
  }

  // merge the 8 sorted chunk lists -> d20 (global loads, independent of LDS)
#define LOAD_VAL(i) unsigned int v##i = cv[(size_t)i * ROW_G + r];
  LOAD_VAL(0) LOAD_VAL(1) LOAD_VAL(2) LOAD_VAL(3) LOAD_VAL(4)
  LOAD_VAL(5) LOAD_VAL(6) LOAD_VAL(7) LOAD_VAL(8) LOAD_VAL(9)
  LOAD_VAL(10) LOAD_VAL(11) LOAD_VAL(12) LOAD_VAL(13) LOAD_VAL(14)
  LOAD_VAL(15) LOAD_VAL(16) LOAD_VAL(17) LOAD_VAL(18) LOAD_VAL(19)
#undef LOAD_VAL
  for (int i = K_NN; i < 8 * K_NN; ++i)
    INSERT_VAL(cv[(size_t)i * ROW_G + r]);
  const unsigned int d20 = v19;

  __syncthreads();

  const int n = r & (NN - 1);
  const float4 ctr = cand[n];
  const float cx = ctr.x, cy = ctr.y, cz = ctr.z, csq = ctr.w;

  int* op = idx_out + (size_t)r * K_NN;
  int cg = 0, ce = 0;
#pragma unroll 4
  for (int i = 0; i < NN; ++i) {
    const float4 c = cand[i];
    const float inner = fmaf(cz, c.z, fmaf(cy, c.y, cx*c.x));
    const float d = 2.0f * inner - csq - c.w;      // bit-identical to stage 1
    const unsigned int u = sortable(d);
    if (u > d20) { if (cg < K_NN) op[cg++] = i; }
    else if (u == d20) { if (ce < K_NN) eq[threadIdx.x][ce++] = (unsigned short)i; }
  }
  for (int j = 0; cg < K_NN; ++j, ++cg) op[cg] = (int)eq[threadIdx.x][j];
}

// ---------------------------------------------------------------------------
// EdgeConv: h = max_k act(W0 @ [x_nbr - x, x] + b0) -> cat cols [0,64)
// 64 lanes = 64 output channels, 4 points/block
// ---------------------------------------------------------------------------
__global__ __launch_bounds__(256) void edgeconv_kernel(const float* __restrict__ x,
    const int* __restrict__ idx, const float* __restrict__ W0,
    const float* __restrict__ b0, float* __restrict__ cat) {
  const int o  = threadIdx.x & 63;
  const int pt = blockIdx.x * 4 + (threadIdx.x >> 6);
  const int b  = pt >> 11, n = pt & (NN - 1);
  const float* xb = x + (size_t)b * NN * 3;

  const float w0 = W0[o*6+0], w1 = W0[o*6+1], w2 = W0[o*6+2];
  const float w3 = W0[o*6+3], w4 = W0[o*6+4], w5 = W0[o*6+5];
  const float bias = b0[o];
  const float cx = xb[n*3+0], cy = xb[n*3+1], cz = xb[n*3+2];

  const int* ip = idx + (size_t)pt * K_NN;
  float px = 0.f, py = 0.f, pz = 0.f;
  if (o < K_NN) { const int m = ip[o]; px = xb[m*3+0]; py = xb[m*3+1]; pz = xb[m*3+2]; }

  float best = NEG_INF;
#pragma unroll
  for (int k = 0; k < K_NN; ++k) {
    const float ax = __shfl(px, k, 64), ay = __shfl(py, k, 64), az = __shfl(pz, k, 64);
    float h = w0 * (ax - cx);
    h = fmaf(w1, ay - cy, h);
    h = fmaf(w2, az - cz, h);
    h = fmaf(w3, cx, h);
    h = fmaf(w4, cy, h);
    h = fmaf(w5, cz, h);
    h += bias;
    h = (h > 0.f) ? h : 0.2f * h;
    best = fmaxf(best, h);
  }
  cat[(size_t)pt * CATC + o] = best;
}

// ---------------------------------------------------------------------------
// pool (max over fixed kNN graph) + 1x1 conv + leaky relu.
// Reads cat cols [coff_in, coff_in+CIN), writes [coff_out, coff_out+COUT).
// ---------------------------------------------------------------------------
template<int CIN, int COUT, int PTS>
__global__ __launch_bounds__(256) void pool_mlp_kernel(float* __restrict__ cat,
    const int* __restrict__ idx, const float* __restrict__ W,
    const float* __restrict__ bias, int coff_in, int coff_out) {
  __shared__ float pooled[PTS][CIN];
  __shared__ int sidx[PTS][K_NN];
  const int pt0 = blockIdx.x * PTS;

  for (int t = threadIdx.x; t < PTS * K_NN; t += 256)
    sidx[t / K_NN][t % K_NN] = idx[(size_t)pt0 * K_NN + t];
  __syncthreads();

  for (int t = threadIdx.x; t < PTS * CIN; t += 256) {
    const int p = t / CIN, c = t % CIN;
    const int bq = (pt0 + p) >> 11;
    const float* base = cat + (size_t)bq * NN * CATC + coff_in + c;
    float mv = NEG_INF;
#pragma unroll
    for (int k = 0; k < K_NN; ++k)
      mv = fmaxf(mv, base[(size_t)sidx[p][k] * CATC]);
    pooled[p][c] = mv;
  }
  __syncthreads();

  for (int t = threadIdx.x; t < PTS * COUT; t += 256) {
    const int p = t / COUT, o = t % COUT;
    const float4* pp = (const float4*)&pooled[p][0];
    const float4* wp = (const float4*)(W + (size_t)o * CIN);
    float acc = 0.f;
#pragma unroll
    for (int c4 = 0; c4 < CIN / 4; ++c4) {
      const float4 pv = pp[c4], wv = wp[c4];
      acc = fmaf(pv.x, wv.x, acc);
      acc = fmaf(pv.y, wv.y, acc);
      acc = fmaf(pv.z, wv.z, acc);
      acc = fmaf(pv.w, wv.w, acc);
    }
    float h = acc + bias[o];
    h = (h > 0.f) ? h : 0.2f * h;
    cat[(size_t)(pt0 + p) * CATC + coff_out + o] = h;
  }
}

// ---------------------------------------------------------------------------
// Final: out[b,o] = act(bf[o] + max_n cat[b,n,:] . Wf[o,:])
// 128x128 tile, 8x8 micro-tile, fp32 FMA, running max -> partials[b][chunk][1024]
// ---------------------------------------------------------------------------
__global__ __launch_bounds__(256) void final_gemm_kernel(const float* __restrict__ cat,
    const float* __restrict__ Wf, float* __restrict__ partials) {
  __shared__ float As[16][132];
  __shared__ float Ws[16][132];
  __shared__ float smax[16][128];
  const int ot = blockIdx.x;       // 8 output tiles of 128
  const int chunk = blockIdx.y;    // 16 row chunks of 128
  const int b = blockIdx.z;
  const int tid = threadIdx.x;
  const int trow = tid >> 4, tcol = tid & 15;
  const float* Abase = cat + ((size_t)b * NN + (size_t)chunk * 128) * CATC;
  const float* Wbase = Wf + (size_t)ot * 128 * CATC;

  float acc[8][8];
#pragma unroll
  for (int p = 0; p < 8; ++p)
#pragma unroll
    for (int q = 0; q < 8; ++q) acc[p][q] = 0.f;

  const int li = tid >> 2;        // 0..63
  const int lj = (tid & 3) * 4;   // 0,4,8,12
  for (int kt = 0; kt < 32; ++kt) {
    const int k0 = kt * 16;
    const float4 a0 = *(const float4*)(Abase + (size_t)li * CATC + k0 + lj);
    const float4 a1 = *(const float4*)(Abase + (size_t)(li + 64) * CATC + k0 + lj);
    const float4 w0 = *(const float4*)(Wbase + (size_t)li * CATC + k0 + lj);
    const float4 w1 = *(const float4*)(Wbase + (size_t)(li + 64) * CATC + k0 + lj);
    __syncthreads();  // previous iteration's LDS reads complete
    As[lj+0][li] = a0.x; As[lj+1][li] = a0.y; As[lj+2][li] = a0.z; As[lj+3][li] = a0.w;
    As[lj+0][li+64] = a1.x; As[lj+1][li+64] = a1.y; As[lj+2][li+64] = a1.z; As[lj+3][li+64] = a1.w;
    Ws[lj+0][li] = w0.x; Ws[lj+1][li] = w0.y; Ws[lj+2][li] = w0.z; Ws[lj+3][li] = w0.w;
    Ws[lj+0][li+64] = w1.x; Ws[lj+1][li+64] = w1.y; Ws[lj+2][li+64] = w1.z; Ws[lj+3][li+64] = w1.w;
    __syncthreads();
#pragma unroll
    for (int kk = 0; kk < 16; ++kk) {
      float a[8], w[8];
      *(float4*)&a[0] = *(const float4*)&As[kk][trow * 8];
      *(float4*)&a[4] = *(const float4*)&As[kk][trow * 8 + 4];
      *(float4*)&w[0] = *(const float4*)&Ws[kk][tcol * 8];
      *(float4*)&w[4] = *(const float4*)&Ws[kk][tcol * 8 + 4];
#pragma unroll
      for (int p = 0; p < 8; ++p)
#pragma unroll
        for (int q = 0; q < 8; ++q)
          acc[p][q] = fmaf(a[p], w[q], acc[p][q]);
    }
  }

  float cmax[8];
#pragma unroll
  for (int q = 0; q < 8; ++q) {
    float m = acc[0][q];
#pragma unroll
    for (int p = 1; p < 8; ++p) m = fmaxf(m, acc[p][q]);
    cmax[q] = m;
  }
  __syncthreads();
#pragma unroll
  for (int q = 0; q < 8; ++q) smax[trow][tcol * 8 + q] = cmax[q];
  __syncthreads();
  if (tid < 128) {
    float m = smax[0][tid];
#pragma unroll
    for (int r = 1; r < 16; ++r) m = fmaxf(m, smax[r][tid]);
    partials[((size_t)(b * 16 + chunk)) * 1024 + (size_t)ot * 128 + tid] = m;
  }
}

__global__ __launch_bounds__(256) void final_reduce_kernel(const float* __restrict__ partials,
    const float* __restrict__ bf, float* __restrict__ out) {
  const int t = blockIdx.x * 256 + threadIdx.x;   // 16384
  const int b = t >> 10, o = t & 1023;
  float m = NEG_INF;
#pragma unroll
  for (int c = 0; c < 16; ++c)
    m = fmaxf(m, partials[((size_t)(b * 16 + c)) * 1024 + o]);
  float h = m + bf[o];
  out[t] = (h > 0.f) ? h : 0.2f * h;   // act(max+b) == max(act(.+b)) (monotone)
}

// ---------------------------------------------------------------------------
extern "C" void kernel_launch(void* const* d_in, const int* in_sizes, int n_in,
                              void* d_out, int out_size, void* d_ws, size_t ws_size,
                              hipStream_t stream) {
  (void)in_sizes; (void)n_in; (void)out_size; (void)ws_size;
  const float* x  = (const float*)d_in[0];
  const float* W0 = (const float*)d_in[1];
  const float* b0 = (const float*)d_in[2];
  const float* W1 = (const float*)d_in[3];
  const float* b1 = (const float*)d_in[4];
  const float* W2 = (const float*)d_in[5];
  const float* b2 = (const float*)d_in[6];
  const float* W3 = (const float*)d_in[7];
  const float* b3 = (const float*)d_in[8];
  const float* Wf = (const float*)d_in[9];
  const float* bf = (const float*)d_in[10];
  float* out = (float*)d_out;

  // ws layout (bytes):
  //   [0, 2621440)                : idx (int, B*N*20)
  //   [2621440, +21.0MB)          : cv  (u32 values, 160*32768) -- dead after recover
  //   [2621440, +67.1MB)          : cat (float, B*N*512)        -- aliases cv (stream order)
  //   [69730304, +1MB)            : partials (float, 16*16*1024)
  char* ws = (char*)d_ws;
  int* idx_ws = (int*)ws;
  unsigned int* cv = (unsigned int*)(ws + 2621440);
  float* cat = (float*)(ws + 2621440);
  float* partials = (float*)(ws + 2621440 + 67108864);

  knn_chunk_kernel<<<BB * 16 * 8, 128, 0, stream>>>(x, cv);
  knn_recover_kernel<<<ROW_G / 256, 256, 0, stream>>>(x, cv, idx_ws);
  edgeconv_kernel<<<ROW_G / 4, 256, 0, stream>>>(x, idx_ws, W0, b0, cat);
  pool_mlp_kernel<64, 64, 16><<<ROW_G / 16, 256, 0, stream>>>(cat, idx_ws, W1, b1, 0, 64);
  pool_mlp_kernel<64, 128, 8><<<ROW_G / 8, 256, 0, stream>>>(cat, idx_ws, W2, b2, 64, 128);
  pool_mlp_kernel<128, 256, 8><<<ROW_G / 8, 256, 0, stream>>>(cat, idx_ws, W3, b3, 128, 256);
  final_gemm_kernel<<<dim3(8, 16, BB), 256, 0, stream>>>(cat, Wf, partials);
  final_reduce_kernel<<<BB * 1024 / 256, 256, 0, stream>>>(partials, bf, out);
}

// Round 5
// 783.822 us; speedup vs baseline: 1.4559x; 1.3175x over previous
//
#include <hip/hip_runtime.h>

#define K_NN 20
#define NEG_INF (-__builtin_inff())

constexpr int BB   = 16;
constexpr int NN   = 2048;
constexpr int CATC = 512;                 // concat feature width
constexpr int ROW_G = BB * NN;            // 32768 points total

typedef short bf16x8 __attribute__((ext_vector_type(8)));   // 8 bf16 = 4 VGPR
typedef float f32x4  __attribute__((ext_vector_type(4)));

// ---------------- bf16 split helpers (hi = rn(a), lo = rn(a - hi)) ----------
__device__ __forceinline__ unsigned short f2bf_rn(float f) {
  unsigned int u = __float_as_uint(f);
  unsigned int r = u + 0x7FFFu + ((u >> 16) & 1u);
  return (unsigned short)(r >> 16);
}
__device__ __forceinline__ float bf2f(unsigned short h) {
  return __uint_as_float((unsigned int)h << 16);
}
__device__ __forceinline__ void split_store(float v, unsigned short* ph, unsigned short* pl) {
  const unsigned short h = f2bf_rn(v);
  *ph = h;
  *pl = f2bf_rn(v - bf2f(h));
}
__device__ __forceinline__ float join_hl(unsigned short h, unsigned short l) {
  return bf2f(h) + bf2f(l);
}

// ---------------------------------------------------------------------------
// Branch-free u32 top-20 VALUE network (desc, duplicates kept).
// ---------------------------------------------------------------------------
#define DECL_VALS(INIT) \
  unsigned int v0=INIT,v1=INIT,v2=INIT,v3=INIT,v4=INIT,v5=INIT,v6=INIT,v7=INIT, \
               v8=INIT,v9=INIT,v10=INIT,v11=INIT,v12=INIT,v13=INIT,v14=INIT,    \
               v15=INIT,v16=INIT,v17=INIT,v18=INIT,v19=INIT;

#define INSERT_VAL(x) do {                         \
    v19 = min(v18, max(v19, (x)));                 \
    v18 = min(v17, max(v18, (x)));                 \
    v17 = min(v16, max(v17, (x)));                 \
    v16 = min(v15, max(v16, (x)));                 \
    v15 = min(v14, max(v15, (x)));                 \
    v14 = min(v13, max(v14, (x)));                 \
    v13 = min(v12, max(v13, (x)));                 \
    v12 = min(v11, max(v12, (x)));                 \
    v11 = min(v10, max(v11, (x)));                 \
    v10 = min(v9,  max(v10, (x)));                 \
    v9  = min(v8,  max(v9,  (x)));                 \
    v8  = min(v7,  max(v8,  (x)));                 \
    v7  = min(v6,  max(v7,  (x)));                 \
    v6  = min(v5,  max(v6,  (x)));                 \
    v5  = min(v4,  max(v5,  (x)));                 \
    v4  = min(v3,  max(v4,  (x)));                 \
    v3  = min(v2,  max(v3,  (x)));                 \
    v2  = min(v1,  max(v2,  (x)));                 \
    v1  = min(v0,  max(v1,  (x)));                 \
    v0  = max(v0, (x));                            \
  } while (0)

__device__ __forceinline__ unsigned int sortable(float d) {
  unsigned int ub = __float_as_uint(d);
  return (ub & 0x80000000u) ? ~ub : (ub | 0x80000000u);
}

// ---------------------------------------------------------------------------
// kNN stage 1: per (batch, row-tile 128, candidate-chunk 256) top-20 values.
// ---------------------------------------------------------------------------
__global__ __launch_bounds__(128) void knn_chunk_kernel(const float* __restrict__ x,
                                                        unsigned int* __restrict__ cv) {
  __shared__ float4 cand[256];           // {x, y, z, sq} per candidate
  const int bid = blockIdx.x;
  const int ch = bid & 7;          // candidate chunk (8 x 256)
  const int rt = (bid >> 3) & 15;  // row tile (16 x 128)
  const int b  = bid >> 7;         // batch
  const float* xb = x + (size_t)b * NN * 3;

  for (int i = threadIdx.x; i < 256; i += 128) {
    const int m = ch * 256 + i;
    const float px = xb[m*3+0], py = xb[m*3+1], pz = xb[m*3+2];
    cand[i] = make_float4(px, py, pz, fmaf(pz, pz, fmaf(py, py, px*px)));
  }
  __syncthreads();

  const int n = rt * 128 + threadIdx.x;
  const float cx = xb[n*3+0], cy = xb[n*3+1], cz = xb[n*3+2];
  const float csq = fmaf(cz, cz, fmaf(cy, cy, cx*cx));

  DECL_VALS(0u)

#pragma unroll 4
  for (int i = 0; i < 256; ++i) {
    const float4 c = cand[i];
    const float inner = fmaf(cz, c.z, fmaf(cy, c.y, cx*c.x));
    const float d = 2.0f * inner - csq - c.w;      // same op order as reference
    const unsigned int u = sortable(d);
    INSERT_VAL(u);
  }

  const int rowg = b * NN + n;
#define STORE_VAL(i) cv[(size_t)(ch*K_NN + i) * ROW_G + rowg] = v##i;
  STORE_VAL(0) STORE_VAL(1) STORE_VAL(2) STORE_VAL(3) STORE_VAL(4)
  STORE_VAL(5) STORE_VAL(6) STORE_VAL(7) STORE_VAL(8) STORE_VAL(9)
  STORE_VAL(10) STORE_VAL(11) STORE_VAL(12) STORE_VAL(13) STORE_VAL(14)
  STORE_VAL(15) STORE_VAL(16) STORE_VAL(17) STORE_VAL(18) STORE_VAL(19)
#undef STORE_VAL
}

// ---------------------------------------------------------------------------
// kNN stage 2: merge values -> d20, rescan -> exact top-k index SET.
// ---------------------------------------------------------------------------
__global__ __launch_bounds__(256) void knn_recover_kernel(const float* __restrict__ x,
                                                          const unsigned int* __restrict__ cv,
                                                          int* __restrict__ idx_out) {
  __shared__ float4 cand[NN];            // 32 KB
  __shared__ unsigned short eq[256][K_NN];
  const int r = blockIdx.x * 256 + threadIdx.x;   // global row; block spans one batch
  const int b = r >> 11;
  const float* xb = x + (size_t)b * NN * 3;

  for (int i = threadIdx.x; i < NN; i += 256) {
    const float px = xb[i*3+0], py = xb[i*3+1], pz = xb[i*3+2];
    cand[i] = make_float4(px, py, pz, fmaf(pz, pz, fmaf(py, py, px*px)));
  }

#define LOAD_VAL(i) unsigned int v##i = cv[(size_t)i * ROW_G + r];
  LOAD_VAL(0) LOAD_VAL(1) LOAD_VAL(2) LOAD_VAL(3) LOAD_VAL(4)
  LOAD_VAL(5) LOAD_VAL(6) LOAD_VAL(7) LOAD_VAL(8) LOAD_VAL(9)
  LOAD_VAL(10) LOAD_VAL(11) LOAD_VAL(12) LOAD_VAL(13) LOAD_VAL(14)
  LOAD_VAL(15) LOAD_VAL(16) LOAD_VAL(17) LOAD_VAL(18) LOAD_VAL(19)
#undef LOAD_VAL
  for (int i = K_NN; i < 8 * K_NN; ++i)
    INSERT_VAL(cv[(size_t)i * ROW_G + r]);
  const unsigned int d20 = v19;

  __syncthreads();

  const int n = r & (NN - 1);
  const float4 ctr = cand[n];
  const float cx = ctr.x, cy = ctr.y, cz = ctr.z, csq = ctr.w;

  int* op = idx_out + (size_t)r * K_NN;
  int cg = 0, ce = 0;
#pragma unroll 4
  for (int i = 0; i < NN; ++i) {
    const float4 c = cand[i];
    const float inner = fmaf(cz, c.z, fmaf(cy, c.y, cx*c.x));
    const float d = 2.0f * inner - csq - c.w;      // bit-identical to stage 1
    const unsigned int u = sortable(d);
    if (u > d20) { if (cg < K_NN) op[cg++] = i; }
    else if (u == d20) { if (ce < K_NN) eq[threadIdx.x][ce++] = (unsigned short)i; }
  }
  for (int j = 0; cg < K_NN; ++j, ++cg) op[cg] = (int)eq[threadIdx.x][j];
}

// ---------------------------------------------------------------------------
// EdgeConv -> split bf16 planes Ah/Al cols [0,64)
// ---------------------------------------------------------------------------
__global__ __launch_bounds__(256) void edgeconv_kernel(const float* __restrict__ x,
    const int* __restrict__ idx, const float* __restrict__ W0,
    const float* __restrict__ b0, unsigned short* __restrict__ Ahg,
    unsigned short* __restrict__ Alg) {
  const int o  = threadIdx.x & 63;
  const int pt = blockIdx.x * 4 + (threadIdx.x >> 6);
  const int b  = pt >> 11, n = pt & (NN - 1);
  const float* xb = x + (size_t)b * NN * 3;

  const float w0 = W0[o*6+0], w1 = W0[o*6+1], w2 = W0[o*6+2];
  const float w3 = W0[o*6+3], w4 = W0[o*6+4], w5 = W0[o*6+5];
  const float bias = b0[o];
  const float cx = xb[n*3+0], cy = xb[n*3+1], cz = xb[n*3+2];

  const int* ip = idx + (size_t)pt * K_NN;
  float px = 0.f, py = 0.f, pz = 0.f;
  if (o < K_NN) { const int m = ip[o]; px = xb[m*3+0]; py = xb[m*3+1]; pz = xb[m*3+2]; }

  float best = NEG_INF;
#pragma unroll
  for (int k = 0; k < K_NN; ++k) {
    const float ax = __shfl(px, k, 64), ay = __shfl(py, k, 64), az = __shfl(pz, k, 64);
    float h = w0 * (ax - cx);
    h = fmaf(w1, ay - cy, h);
    h = fmaf(w2, az - cz, h);
    h = fmaf(w3, cx, h);
    h = fmaf(w4, cy, h);
    h = fmaf(w5, cz, h);
    h += bias;
    h = (h > 0.f) ? h : 0.2f * h;
    best = fmaxf(best, h);
  }
  split_store(best, &Ahg[(size_t)pt * CATC + o], &Alg[(size_t)pt * CATC + o]);
}

// ---------------------------------------------------------------------------
// pool (max over kNN graph, reading split h+l) + 1x1 conv + act -> split store
// ---------------------------------------------------------------------------
template<int CIN, int COUT, int PTS>
__global__ __launch_bounds__(256) void pool_mlp_kernel(
    unsigned short* __restrict__ Ahg, unsigned short* __restrict__ Alg,
    const int* __restrict__ idx, const float* __restrict__ W,
    const float* __restrict__ bias, int coff_in, int coff_out) {
  __shared__ float pooled[PTS][CIN];
  __shared__ int sidx[PTS][K_NN];
  const int pt0 = blockIdx.x * PTS;

  for (int t = threadIdx.x; t < PTS * K_NN; t += 256)
    sidx[t / K_NN][t % K_NN] = idx[(size_t)pt0 * K_NN + t];
  __syncthreads();

  for (int t = threadIdx.x; t < PTS * CIN; t += 256) {
    const int p = t / CIN, c = t % CIN;
    const int bq = (pt0 + p) >> 11;
    const size_t base = (size_t)bq * NN * CATC + coff_in + c;
    float mv = NEG_INF;
#pragma unroll
    for (int k = 0; k < K_NN; ++k) {
      const size_t a = base + (size_t)sidx[p][k] * CATC;
      mv = fmaxf(mv, join_hl(Ahg[a], Alg[a]));
    }
    pooled[p][c] = mv;
  }
  __syncthreads();

  for (int t = threadIdx.x; t < PTS * COUT; t += 256) {
    const int p = t / COUT, o = t % COUT;
    const float4* pp = (const float4*)&pooled[p][0];
    const float4* wp = (const float4*)(W + (size_t)o * CIN);
    float acc = 0.f;
#pragma unroll
    for (int c4 = 0; c4 < CIN / 4; ++c4) {
      const float4 pv = pp[c4], wv = wp[c4];
      acc = fmaf(pv.x, wv.x, acc);
      acc = fmaf(pv.y, wv.y, acc);
      acc = fmaf(pv.z, wv.z, acc);
      acc = fmaf(pv.w, wv.w, acc);
    }
    float h = acc + bias[o];
    h = (h > 0.f) ? h : 0.2f * h;
    const size_t a = (size_t)(pt0 + p) * CATC + coff_out + o;
    split_store(h, &Ahg[a], &Alg[a]);
  }
}

// ---------------------------------------------------------------------------
// Split Wf (1024x512 f32) -> Wh, Wl bf16
// ---------------------------------------------------------------------------
__global__ __launch_bounds__(256) void wsplit_kernel(const float* __restrict__ Wf,
    unsigned short* __restrict__ Wh, unsigned short* __restrict__ Wl) {
  const int t = blockIdx.x * 256 + threadIdx.x;   // 131072 float4 groups
  const float4 v = ((const float4*)Wf)[t];
  ushort4 h4, l4;
  h4.x = f2bf_rn(v.x); l4.x = f2bf_rn(v.x - bf2f(h4.x));
  h4.y = f2bf_rn(v.y); l4.y = f2bf_rn(v.y - bf2f(h4.y));
  h4.z = f2bf_rn(v.z); l4.z = f2bf_rn(v.z - bf2f(h4.z));
  h4.w = f2bf_rn(v.w); l4.w = f2bf_rn(v.w - bf2f(h4.w));
  ((ushort4*)Wh)[t] = h4;
  ((ushort4*)Wl)[t] = l4;
}

// ---------------------------------------------------------------------------
// Final GEMM via bf16x3 MFMA: C = A.Wf^T, running max over rows -> partials.
// 128x128 tile, BK=32, 4 waves (2x2), per-wave 64x64 = 4x4 16x16x32 frags.
// acc += Ah.Wh + Ah.Wl + Al.Wh  (err ~2^-16 rel).
// LDS rows padded 32->40 bf16 (80 B) => frag ds_read_b128 2-way (free).
// ---------------------------------------------------------------------------
__global__ __launch_bounds__(256) void final_gemm_mfma(
    const unsigned short* __restrict__ Ahg, const unsigned short* __restrict__ Alg,
    const unsigned short* __restrict__ Whg, const unsigned short* __restrict__ Wlg,
    float* __restrict__ partials) {
  __shared__ __align__(16) unsigned short AhL[128][40];
  __shared__ __align__(16) unsigned short AlL[128][40];
  __shared__ __align__(16) unsigned short WhL[128][40];
  __shared__ __align__(16) unsigned short WlL[128][40];
  __shared__ float smax[2][128];

  const int ot    = blockIdx.x;    // 8 col tiles of 128
  const int chunk = blockIdx.y;    // 16 row chunks of 128
  const int b     = blockIdx.z;
  const int tid   = threadIdx.x;
  const int lane  = tid & 63;
  const int w     = tid >> 6;      // wave 0..3
  const int wr    = w >> 1;        // row half (64)
  const int wc    = w & 1;         // col half (64)
  const int fr    = lane & 15;     // fragment row/col within 16
  const int kg    = lane >> 4;     // k-group 0..3 (k = kg*8 + j)

  // staging assignment: thread t covers row t>>1, 16 k's at half=(t&1)*16
  const int srow = tid >> 1;
  const int shalf = (tid & 1) * 16;
  const size_t arow = ((size_t)(b * NN) + (size_t)chunk * 128 + srow) * CATC;
  const size_t wrow = ((size_t)ot * 128 + srow) * CATC;

  f32x4 acc[4][4];
#pragma unroll
  for (int i = 0; i < 4; ++i)
#pragma unroll
    for (int j = 0; j < 4; ++j) acc[i][j] = (f32x4){0.f, 0.f, 0.f, 0.f};

  for (int kt = 0; kt < 16; ++kt) {
    const int k0 = kt * 32;
    // ---- stage 32-k panel (bf16 h/l for A and W) ----
    const uint4 a0 = *(const uint4*)(Ahg + arow + k0 + shalf);
    const uint4 a1 = *(const uint4*)(Ahg + arow + k0 + shalf + 8);
    const uint4 a2 = *(const uint4*)(Alg + arow + k0 + shalf);
    const uint4 a3 = *(const uint4*)(Alg + arow + k0 + shalf + 8);
    const uint4 w0 = *(const uint4*)(Whg + wrow + k0 + shalf);
    const uint4 w1 = *(const uint4*)(Whg + wrow + k0 + shalf + 8);
    const uint4 w2 = *(const uint4*)(Wlg + wrow + k0 + shalf);
    const uint4 w3 = *(const uint4*)(Wlg + wrow + k0 + shalf + 8);
    __syncthreads();   // prior iteration's frag reads complete
    *(uint4*)&AhL[srow][shalf]     = a0;
    *(uint4*)&AhL[srow][shalf + 8] = a1;
    *(uint4*)&AlL[srow][shalf]     = a2;
    *(uint4*)&AlL[srow][shalf + 8] = a3;
    *(uint4*)&WhL[srow][shalf]     = w0;
    *(uint4*)&WhL[srow][shalf + 8] = w1;
    *(uint4*)&WlL[srow][shalf]     = w2;
    *(uint4*)&WlL[srow][shalf + 8] = w3;
    __syncthreads();

    // ---- fragment loads ----
    bf16x8 ahf[4], alf[4], whf[4], wlf[4];
#pragma unroll
    for (int i = 0; i < 4; ++i) {
      ahf[i] = *(const bf16x8*)&AhL[wr * 64 + i * 16 + fr][kg * 8];
      alf[i] = *(const bf16x8*)&AlL[wr * 64 + i * 16 + fr][kg * 8];
    }
#pragma unroll
    for (int j = 0; j < 4; ++j) {
      whf[j] = *(const bf16x8*)&WhL[wc * 64 + j * 16 + fr][kg * 8];
      wlf[j] = *(const bf16x8*)&WlL[wc * 64 + j * 16 + fr][kg * 8];
    }

    // ---- 48 MFMA ----
#pragma unroll
    for (int i = 0; i < 4; ++i)
#pragma unroll
      for (int j = 0; j < 4; ++j) {
        acc[i][j] = __builtin_amdgcn_mfma_f32_16x16x32_bf16(ahf[i], whf[j], acc[i][j], 0, 0, 0);
        acc[i][j] = __builtin_amdgcn_mfma_f32_16x16x32_bf16(ahf[i], wlf[j], acc[i][j], 0, 0, 0);
        acc[i][j] = __builtin_amdgcn_mfma_f32_16x16x32_bf16(alf[i], whf[j], acc[i][j], 0, 0, 0);
      }
  }

  // ---- epilogue: max over the wave's 64 rows per output col ----
  // C/D mapping: col = (lane&15) + j*16 + wc*64, rows covered by (i, kg, reg).
#pragma unroll
  for (int j = 0; j < 4; ++j) {
    float mj = NEG_INF;
#pragma unroll
    for (int i = 0; i < 4; ++i) {
      mj = fmaxf(mj, fmaxf(fmaxf(acc[i][j][0], acc[i][j][1]),
                           fmaxf(acc[i][j][2], acc[i][j][3])));
    }
    mj = fmaxf(mj, __shfl_xor(mj, 16, 64));
    mj = fmaxf(mj, __shfl_xor(mj, 32, 64));   // all lanes: max over 64 rows
    if (lane < 16) smax[wr][wc * 64 + j * 16 + fr] = mj;
  }
  __syncthreads();
  if (tid < 128) {
    const float m = fmaxf(smax[0][tid], smax[1][tid]);
    partials[((size_t)(b * 16 + chunk)) * 1024 + (size_t)ot * 128 + tid] = m;
  }
}

__global__ __launch_bounds__(256) void final_reduce_kernel(const float* __restrict__ partials,
    const float* __restrict__ bf, float* __restrict__ out) {
  const int t = blockIdx.x * 256 + threadIdx.x;   // 16384
  const int b = t >> 10, o = t & 1023;
  float m = NEG_INF;
#pragma unroll
  for (int c = 0; c < 16; ++c)
    m = fmaxf(m, partials[((size_t)(b * 16 + c)) * 1024 + o]);
  float h = m + bf[o];
  out[t] = (h > 0.f) ? h : 0.2f * h;   // act(max+b) == max(act(.+b)) (monotone)
}

// ---------------------------------------------------------------------------
extern "C" void kernel_launch(void* const* d_in, const int* in_sizes, int n_in,
                              void* d_out, int out_size, void* d_ws, size_t ws_size,
                              hipStream_t stream) {
  (void)in_sizes; (void)n_in; (void)out_size; (void)ws_size;
  const float* x  = (const float*)d_in[0];
  const float* W0 = (const float*)d_in[1];
  const float* b0 = (const float*)d_in[2];
  const float* W1 = (const float*)d_in[3];
  const float* b1 = (const float*)d_in[4];
  const float* W2 = (const float*)d_in[5];
  const float* b2 = (const float*)d_in[6];
  const float* W3 = (const float*)d_in[7];
  const float* b3 = (const float*)d_in[8];
  const float* Wf = (const float*)d_in[9];
  const float* bf = (const float*)d_in[10];
  float* out = (float*)d_out;

  // ws layout (bytes), total 70,778,880 (same as validated round-0 footprint):
  //   [0, 2621440)           : idx (int 32768x20) -- dead after pool3;
  //                            then Wh [0,1MB) + Wl [1MB,2MB) alias (wsplit after pool3)
  //   [2621440, 23592960)    : cv (u32 160x32768) -- dead after recover, aliased under Ah
  //   [2621440, 36175872)    : Ah bf16[32768][512]
  //   [36175872, 69730304)   : Al bf16[32768][512]
  //   [69730304, 70778880)   : partials (float 16*16*1024)
  char* ws = (char*)d_ws;
  int* idx_ws = (int*)ws;
  unsigned short* Wh = (unsigned short*)ws;
  unsigned short* Wl = (unsigned short*)(ws + 1048576);
  unsigned int* cv = (unsigned int*)(ws + 2621440);
  unsigned short* Ah = (unsigned short*)(ws + 2621440);
  unsigned short* Al = (unsigned short*)(ws + 36175872);
  float* partials = (float*)(ws + 69730304);

  knn_chunk_kernel<<<BB * 16 * 8, 128, 0, stream>>>(x, cv);
  knn_recover_kernel<<<ROW_G / 256, 256, 0, stream>>>(x, cv, idx_ws);
  edgeconv_kernel<<<ROW_G / 4, 256, 0, stream>>>(x, idx_ws, W0, b0, Ah, Al);
  pool_mlp_kernel<64, 64, 16><<<ROW_G / 16, 256, 0, stream>>>(Ah, Al, idx_ws, W1, b1, 0, 64);
  pool_mlp_kernel<64, 128, 8><<<ROW_G / 8, 256, 0, stream>>>(Ah, Al, idx_ws, W2, b2, 64, 128);
  pool_mlp_kernel<128, 256, 8><<<ROW_G / 8, 256, 0, stream>>>(Ah, Al, idx_ws, W3, b3, 128, 256);
  wsplit_kernel<<<512, 256, 0, stream>>>(Wf, Wh, Wl);
  final_gemm_mfma<<<dim3(8, 16, BB), 256, 0, stream>>>(Ah, Al, Wh, Wl, partials);
  final_reduce_kernel<<<BB * 1024 / 256, 256, 0, stream>>>(partials, bf, out);
}

// Round 6
// 534.168 us; speedup vs baseline: 2.1363x; 1.4674x over previous
//
#include <hip/hip_runtime.h>

#define K_NN 20
#define NEG_INF (-__builtin_inff())

constexpr int BB   = 16;
constexpr int NN   = 2048;
constexpr int CATC = 512;                 // concat feature width
constexpr int ROW_G = BB * NN;            // 32768 points total

typedef short bf16x8 __attribute__((ext_vector_type(8)));   // 8 bf16 = 4 VGPR
typedef float f32x4  __attribute__((ext_vector_type(4)));

// ---------------- bf16 split helpers (hi = rn(a), lo = rn(a - hi)) ----------
__device__ __forceinline__ unsigned short f2bf_rn(float f) {
  unsigned int u = __float_as_uint(f);
  unsigned int r = u + 0x7FFFu + ((u >> 16) & 1u);
  return (unsigned short)(r >> 16);
}
__device__ __forceinline__ float bf2f(unsigned short h) {
  return __uint_as_float((unsigned int)h << 16);
}
__device__ __forceinline__ void split_store(float v, unsigned short* ph, unsigned short* pl) {
  const unsigned short h = f2bf_rn(v);
  *ph = h;
  *pl = f2bf_rn(v - bf2f(h));
}
__device__ __forceinline__ float join_hl(unsigned short h, unsigned short l) {
  return bf2f(h) + bf2f(l);
}

__device__ __forceinline__ int mbcnt(unsigned long long mask) {   // popc(mask & lanes_below)
  return __builtin_amdgcn_mbcnt_hi((unsigned int)(mask >> 32),
         __builtin_amdgcn_mbcnt_lo((unsigned int)mask, 0));
}

// ---------------------------------------------------------------------------
// Branch-free u32 top-20 VALUE network (desc, duplicates kept).
// ---------------------------------------------------------------------------
#define DECL_VALS(INIT) \
  unsigned int v0=INIT,v1=INIT,v2=INIT,v3=INIT,v4=INIT,v5=INIT,v6=INIT,v7=INIT, \
               v8=INIT,v9=INIT,v10=INIT,v11=INIT,v12=INIT,v13=INIT,v14=INIT,    \
               v15=INIT,v16=INIT,v17=INIT,v18=INIT,v19=INIT;

#define INSERT_VAL(x) do {                         \
    v19 = min(v18, max(v19, (x)));                 \
    v18 = min(v17, max(v18, (x)));                 \
    v17 = min(v16, max(v17, (x)));                 \
    v16 = min(v15, max(v16, (x)));                 \
    v15 = min(v14, max(v15, (x)));                 \
    v14 = min(v13, max(v14, (x)));                 \
    v13 = min(v12, max(v13, (x)));                 \
    v12 = min(v11, max(v12, (x)));                 \
    v11 = min(v10, max(v11, (x)));                 \
    v10 = min(v9,  max(v10, (x)));                 \
    v9  = min(v8,  max(v9,  (x)));                 \
    v8  = min(v7,  max(v8,  (x)));                 \
    v7  = min(v6,  max(v7,  (x)));                 \
    v6  = min(v5,  max(v6,  (x)));                 \
    v5  = min(v4,  max(v5,  (x)));                 \
    v4  = min(v3,  max(v4,  (x)));                 \
    v3  = min(v2,  max(v3,  (x)));                 \
    v2  = min(v1,  max(v2,  (x)));                 \
    v1  = min(v0,  max(v1,  (x)));                 \
    v0  = max(v0, (x));                            \
  } while (0)

__device__ __forceinline__ unsigned int sortable(float d) {
  unsigned int ub = __float_as_uint(d);
  return (ub & 0x80000000u) ? ~ub : (ub | 0x80000000u);
}

// ---------------------------------------------------------------------------
// kNN stage 1: per (batch, row-tile 128, candidate-chunk 256) top-20 values.
// ---------------------------------------------------------------------------
__global__ __launch_bounds__(128) void knn_chunk_kernel(const float* __restrict__ x,
                                                        unsigned int* __restrict__ cv) {
  __shared__ float4 cand[256];           // {x, y, z, sq} per candidate
  const int bid = blockIdx.x;
  const int ch = bid & 7;          // candidate chunk (8 x 256)
  const int rt = (bid >> 3) & 15;  // row tile (16 x 128)
  const int b  = bid >> 7;         // batch
  const float* xb = x + (size_t)b * NN * 3;

  for (int i = threadIdx.x; i < 256; i += 128) {
    const int m = ch * 256 + i;
    const float px = xb[m*3+0], py = xb[m*3+1], pz = xb[m*3+2];
    cand[i] = make_float4(px, py, pz, fmaf(pz, pz, fmaf(py, py, px*px)));
  }
  __syncthreads();

  const int n = rt * 128 + threadIdx.x;
  const float cx = xb[n*3+0], cy = xb[n*3+1], cz = xb[n*3+2];
  const float csq = fmaf(cz, cz, fmaf(cy, cy, cx*cx));

  DECL_VALS(0u)

#pragma unroll 4
  for (int i = 0; i < 256; ++i) {
    const float4 c = cand[i];
    const float inner = fmaf(cz, c.z, fmaf(cy, c.y, cx*c.x));
    const float d = 2.0f * inner - csq - c.w;      // same op order as reference
    const unsigned int u = sortable(d);
    INSERT_VAL(u);
  }

  const int rowg = b * NN + n;
#define STORE_VAL(i) cv[(size_t)(ch*K_NN + i) * ROW_G + rowg] = v##i;
  STORE_VAL(0) STORE_VAL(1) STORE_VAL(2) STORE_VAL(3) STORE_VAL(4)
  STORE_VAL(5) STORE_VAL(6) STORE_VAL(7) STORE_VAL(8) STORE_VAL(9)
  STORE_VAL(10) STORE_VAL(11) STORE_VAL(12) STORE_VAL(13) STORE_VAL(14)
  STORE_VAL(15) STORE_VAL(16) STORE_VAL(17) STORE_VAL(18) STORE_VAL(19)
#undef STORE_VAL
}

// ---------------------------------------------------------------------------
// kNN stage 2a: merge 8 chunk value-lists -> d20 (20th-largest) per row.
// ---------------------------------------------------------------------------
__global__ __launch_bounds__(64) void knn_d20_kernel(const unsigned int* __restrict__ cv,
                                                     unsigned int* __restrict__ d20g) {
  const int r = blockIdx.x * 64 + threadIdx.x;
#define LOAD_VAL(i) unsigned int v##i = cv[(size_t)i * ROW_G + r];
  LOAD_VAL(0) LOAD_VAL(1) LOAD_VAL(2) LOAD_VAL(3) LOAD_VAL(4)
  LOAD_VAL(5) LOAD_VAL(6) LOAD_VAL(7) LOAD_VAL(8) LOAD_VAL(9)
  LOAD_VAL(10) LOAD_VAL(11) LOAD_VAL(12) LOAD_VAL(13) LOAD_VAL(14)
  LOAD_VAL(15) LOAD_VAL(16) LOAD_VAL(17) LOAD_VAL(18) LOAD_VAL(19)
#undef LOAD_VAL
#pragma unroll 4
  for (int i = K_NN; i < 8 * K_NN; ++i)
    INSERT_VAL(cv[(size_t)i * ROW_G + r]);
  d20g[r] = v19;
}

// ---------------------------------------------------------------------------
// kNN stage 2b: ONE WAVE PER ROW. Rescan 2048 candidates (64/iter), compact
// members (dist > d20, <=19 of them) via ballot; ties (== d20) appended in
// ascending index order (k-major x lane order) -> exact top_k membership.
// ---------------------------------------------------------------------------
__global__ __launch_bounds__(256) void knn_collect_kernel(const float* __restrict__ x,
    const unsigned int* __restrict__ d20g, int* __restrict__ idx_out) {
  __shared__ float4 cand[NN];            // 32 KB, one batch
  __shared__ int tie[4][K_NN];
  const int w = threadIdx.x >> 6, lane = threadIdx.x & 63;
  const int r = blockIdx.x * 4 + w;      // 4 consecutive rows = same batch
  const int b = r >> 11;
  const float* xb = x + (size_t)b * NN * 3;

  for (int i = threadIdx.x; i < NN; i += 256) {
    const float px = xb[i*3+0], py = xb[i*3+1], pz = xb[i*3+2];
    cand[i] = make_float4(px, py, pz, fmaf(pz, pz, fmaf(py, py, px*px)));
  }
  __syncthreads();

  const int n = r & (NN - 1);
  const float4 ctr = cand[n];            // ctr.w == csq, bit-identical to stage 1
  const unsigned int d20 = d20g[r];
  int* op = idx_out + (size_t)r * K_NN;
  int cg = 0, ce = 0;

#pragma unroll 4
  for (int k = 0; k < NN / 64; ++k) {
    const int i = k * 64 + lane;
    const float4 c = cand[i];
    const float inner = fmaf(ctr.z, c.z, fmaf(ctr.y, c.y, ctr.x*c.x));
    const float d = 2.0f * inner - ctr.w - c.w;    // bit-identical to stage 1
    const unsigned int u = sortable(d);
    const unsigned long long mb = __ballot(u > d20);
    if (u > d20) op[cg + mbcnt(mb)] = i;
    cg += __popcll(mb);
    const unsigned long long tb = __ballot(u == d20);
    if (tb) {
      if (u == d20) {
        const int pos = ce + mbcnt(tb);
        if (pos < K_NN) tie[w][pos] = i;           // capped: only need <=20
      }
      ce += __popcll(tb);
    }
  }
  if (lane == 0)
    for (int j = 0; cg < K_NN; ++j, ++cg) op[cg] = tie[w][j];
}

// ---------------------------------------------------------------------------
// EdgeConv -> split bf16 planes Ah/Al cols [0,64)
// ---------------------------------------------------------------------------
__global__ __launch_bounds__(256) void edgeconv_kernel(const float* __restrict__ x,
    const int* __restrict__ idx, const float* __restrict__ W0,
    const float* __restrict__ b0, unsigned short* __restrict__ Ahg,
    unsigned short* __restrict__ Alg) {
  const int o  = threadIdx.x & 63;
  const int pt = blockIdx.x * 4 + (threadIdx.x >> 6);
  const int b  = pt >> 11, n = pt & (NN - 1);
  const float* xb = x + (size_t)b * NN * 3;

  const float w0 = W0[o*6+0], w1 = W0[o*6+1], w2 = W0[o*6+2];
  const float w3 = W0[o*6+3], w4 = W0[o*6+4], w5 = W0[o*6+5];
  const float bias = b0[o];
  const float cx = xb[n*3+0], cy = xb[n*3+1], cz = xb[n*3+2];

  const int* ip = idx + (size_t)pt * K_NN;
  float px = 0.f, py = 0.f, pz = 0.f;
  if (o < K_NN) { const int m = ip[o]; px = xb[m*3+0]; py = xb[m*3+1]; pz = xb[m*3+2]; }

  float best = NEG_INF;
#pragma unroll
  for (int k = 0; k < K_NN; ++k) {
    const float ax = __shfl(px, k, 64), ay = __shfl(py, k, 64), az = __shfl(pz, k, 64);
    float h = w0 * (ax - cx);
    h = fmaf(w1, ay - cy, h);
    h = fmaf(w2, az - cz, h);
    h = fmaf(w3, cx, h);
    h = fmaf(w4, cy, h);
    h = fmaf(w5, cz, h);
    h += bias;
    h = (h > 0.f) ? h : 0.2f * h;
    best = fmaxf(best, h);
  }
  split_store(best, &Ahg[(size_t)pt * CATC + o], &Alg[(size_t)pt * CATC + o]);
}

// ---------------------------------------------------------------------------
// pool (max over kNN graph, reading split h+l) + 1x1 conv + act -> split store
// ---------------------------------------------------------------------------
template<int CIN, int COUT, int PTS>
__global__ __launch_bounds__(256) void pool_mlp_kernel(
    unsigned short* __restrict__ Ahg, unsigned short* __restrict__ Alg,
    const int* __restrict__ idx, const float* __restrict__ W,
    const float* __restrict__ bias, int coff_in, int coff_out) {
  __shared__ float pooled[PTS][CIN];
  __shared__ int sidx[PTS][K_NN];
  const int pt0 = blockIdx.x * PTS;

  for (int t = threadIdx.x; t < PTS * K_NN; t += 256)
    sidx[t / K_NN][t % K_NN] = idx[(size_t)pt0 * K_NN + t];
  __syncthreads();

  for (int t = threadIdx.x; t < PTS * CIN; t += 256) {
    const int p = t / CIN, c = t % CIN;
    const int bq = (pt0 + p) >> 11;
    const size_t base = (size_t)bq * NN * CATC + coff_in + c;
    float mv = NEG_INF;
#pragma unroll
    for (int k = 0; k < K_NN; ++k) {
      const size_t a = base + (size_t)sidx[p][k] * CATC;
      mv = fmaxf(mv, join_hl(Ahg[a], Alg[a]));
    }
    pooled[p][c] = mv;
  }
  __syncthreads();

  for (int t = threadIdx.x; t < PTS * COUT; t += 256) {
    const int p = t / COUT, o = t % COUT;
    const float4* pp = (const float4*)&pooled[p][0];
    const float4* wp = (const float4*)(W + (size_t)o * CIN);
    float acc = 0.f;
#pragma unroll
    for (int c4 = 0; c4 < CIN / 4; ++c4) {
      const float4 pv = pp[c4], wv = wp[c4];
      acc = fmaf(pv.x, wv.x, acc);
      acc = fmaf(pv.y, wv.y, acc);
      acc = fmaf(pv.z, wv.z, acc);
      acc = fmaf(pv.w, wv.w, acc);
    }
    float h = acc + bias[o];
    h = (h > 0.f) ? h : 0.2f * h;
    const size_t a = (size_t)(pt0 + p) * CATC + coff_out + o;
    split_store(h, &Ahg[a], &Alg[a]);
  }
}

// ---------------------------------------------------------------------------
// Split Wf (1024x512 f32) -> Wh, Wl bf16
// ---------------------------------------------------------------------------
__global__ __launch_bounds__(256) void wsplit_kernel(const float* __restrict__ Wf,
    unsigned short* __restrict__ Wh, unsigned short* __restrict__ Wl) {
  const int t = blockIdx.x * 256 + threadIdx.x;   // 131072 float4 groups
  const float4 v = ((const float4*)Wf)[t];
  ushort4 h4, l4;
  h4.x = f2bf_rn(v.x); l4.x = f2bf_rn(v.x - bf2f(h4.x));
  h4.y = f2bf_rn(v.y); l4.y = f2bf_rn(v.y - bf2f(h4.y));
  h4.z = f2bf_rn(v.z); l4.z = f2bf_rn(v.z - bf2f(h4.z));
  h4.w = f2bf_rn(v.w); l4.w = f2bf_rn(v.w - bf2f(h4.w));
  ((ushort4*)Wh)[t] = h4;
  ((ushort4*)Wl)[t] = l4;
}

// ---------------------------------------------------------------------------
// Final GEMM via bf16x3 MFMA: C = A.Wf^T, running max over rows -> partials.
// ---------------------------------------------------------------------------
__global__ __launch_bounds__(256) void final_gemm_mfma(
    const unsigned short* __restrict__ Ahg, const unsigned short* __restrict__ Alg,
    const unsigned short* __restrict__ Whg, const unsigned short* __restrict__ Wlg,
    float* __restrict__ partials) {
  __shared__ __align__(16) unsigned short AhL[128][40];
  __shared__ __align__(16) unsigned short AlL[128][40];
  __shared__ __align__(16) unsigned short WhL[128][40];
  __shared__ __align__(16) unsigned short WlL[128][40];
  __shared__ float smax[2][128];

  const int ot    = blockIdx.x;    // 8 col tiles of 128
  const int chunk = blockIdx.y;    // 16 row chunks of 128
  const int b     = blockIdx.z;
  const int tid   = threadIdx.x;
  const int lane  = tid & 63;
  const int w     = tid >> 6;      // wave 0..3
  const int wr    = w >> 1;        // row half (64)
  const int wc    = w & 1;         // col half (64)
  const int fr    = lane & 15;     // fragment row/col within 16
  const int kg    = lane >> 4;     // k-group 0..3

  const int srow = tid >> 1;
  const int shalf = (tid & 1) * 16;
  const size_t arow = ((size_t)(b * NN) + (size_t)chunk * 128 + srow) * CATC;
  const size_t wrow = ((size_t)ot * 128 + srow) * CATC;

  f32x4 acc[4][4];
#pragma unroll
  for (int i = 0; i < 4; ++i)
#pragma unroll
    for (int j = 0; j < 4; ++j) acc[i][j] = (f32x4){0.f, 0.f, 0.f, 0.f};

  for (int kt = 0; kt < 16; ++kt) {
    const int k0 = kt * 32;
    const uint4 a0 = *(const uint4*)(Ahg + arow + k0 + shalf);
    const uint4 a1 = *(const uint4*)(Ahg + arow + k0 + shalf + 8);
    const uint4 a2 = *(const uint4*)(Alg + arow + k0 + shalf);
    const uint4 a3 = *(const uint4*)(Alg + arow + k0 + shalf + 8);
    const uint4 w0 = *(const uint4*)(Whg + wrow + k0 + shalf);
    const uint4 w1 = *(const uint4*)(Whg + wrow + k0 + shalf + 8);
    const uint4 w2 = *(const uint4*)(Wlg + wrow + k0 + shalf);
    const uint4 w3 = *(const uint4*)(Wlg + wrow + k0 + shalf + 8);
    __syncthreads();
    *(uint4*)&AhL[srow][shalf]     = a0;
    *(uint4*)&AhL[srow][shalf + 8] = a1;
    *(uint4*)&AlL[srow][shalf]     = a2;
    *(uint4*)&AlL[srow][shalf + 8] = a3;
    *(uint4*)&WhL[srow][shalf]     = w0;
    *(uint4*)&WhL[srow][shalf + 8] = w1;
    *(uint4*)&WlL[srow][shalf]     = w2;
    *(uint4*)&WlL[srow][shalf + 8] = w3;
    __syncthreads();

    bf16x8 ahf[4], alf[4], whf[4], wlf[4];
#pragma unroll
    for (int i = 0; i < 4; ++i) {
      ahf[i] = *(const bf16x8*)&AhL[wr * 64 + i * 16 + fr][kg * 8];
      alf[i] = *(const bf16x8*)&AlL[wr * 64 + i * 16 + fr][kg * 8];
    }
#pragma unroll
    for (int j = 0; j < 4; ++j) {
      whf[j] = *(const bf16x8*)&WhL[wc * 64 + j * 16 + fr][kg * 8];
      wlf[j] = *(const bf16x8*)&WlL[wc * 64 + j * 16 + fr][kg * 8];
    }

#pragma unroll
    for (int i = 0; i < 4; ++i)
#pragma unroll
      for (int j = 0; j < 4; ++j) {
        acc[i][j] = __builtin_amdgcn_mfma_f32_16x16x32_bf16(ahf[i], whf[j], acc[i][j], 0, 0, 0);
        acc[i][j] = __builtin_amdgcn_mfma_f32_16x16x32_bf16(ahf[i], wlf[j], acc[i][j], 0, 0, 0);
        acc[i][j] = __builtin_amdgcn_mfma_f32_16x16x32_bf16(alf[i], whf[j], acc[i][j], 0, 0, 0);
      }
  }

#pragma unroll
  for (int j = 0; j < 4; ++j) {
    float mj = NEG_INF;
#pragma unroll
    for (int i = 0; i < 4; ++i) {
      mj = fmaxf(mj, fmaxf(fmaxf(acc[i][j][0], acc[i][j][1]),
                           fmaxf(acc[i][j][2], acc[i][j][3])));
    }
    mj = fmaxf(mj, __shfl_xor(mj, 16, 64));
    mj = fmaxf(mj, __shfl_xor(mj, 32, 64));
    if (lane < 16) smax[wr][wc * 64 + j * 16 + fr] = mj;
  }
  __syncthreads();
  if (tid < 128) {
    const float m = fmaxf(smax[0][tid], smax[1][tid]);
    partials[((size_t)(b * 16 + chunk)) * 1024 + (size_t)ot * 128 + tid] = m;
  }
}

__global__ __launch_bounds__(256) void final_reduce_kernel(const float* __restrict__ partials,
    const float* __restrict__ bf, float* __restrict__ out) {
  const int t = blockIdx.x * 256 + threadIdx.x;   // 16384
  const int b = t >> 10, o = t & 1023;
  float m = NEG_INF;
#pragma unroll
  for (int c = 0; c < 16; ++c)
    m = fmaxf(m, partials[((size_t)(b * 16 + c)) * 1024 + o]);
  float h = m + bf[o];
  out[t] = (h > 0.f) ? h : 0.2f * h;   // act(max+b) == max(act(.+b)) (monotone)
}

// ---------------------------------------------------------------------------
extern "C" void kernel_launch(void* const* d_in, const int* in_sizes, int n_in,
                              void* d_out, int out_size, void* d_ws, size_t ws_size,
                              hipStream_t stream) {
  (void)in_sizes; (void)n_in; (void)out_size; (void)ws_size;
  const float* x  = (const float*)d_in[0];
  const float* W0 = (const float*)d_in[1];
  const float* b0 = (const float*)d_in[2];
  const float* W1 = (const float*)d_in[3];
  const float* b1 = (const float*)d_in[4];
  const float* W2 = (const float*)d_in[5];
  const float* b2 = (const float*)d_in[6];
  const float* W3 = (const float*)d_in[7];
  const float* b3 = (const float*)d_in[8];
  const float* Wf = (const float*)d_in[9];
  const float* bf = (const float*)d_in[10];
  float* out = (float*)d_out;

  // ws layout (bytes), total 70,778,880:
  //   [0, 2621440)           : idx (int 32768x20) -- dead after pool3;
  //                            Wh [0,1MB) + Wl [1MB,2MB) alias (wsplit after pool3)
  //   [2621440, 23592960)    : cv (u32 160x32768) -- dead after d20, aliased under Ah
  //   [23592960, 23724032)   : d20 (u32 32768)    -- dead after collect, under Ah
  //   [2621440, 36175872)    : Ah bf16[32768][512] (written from edgeconv onward)
  //   [36175872, 69730304)   : Al bf16[32768][512]
  //   [69730304, 70778880)   : partials (float 16*16*1024)
  char* ws = (char*)d_ws;
  int* idx_ws = (int*)ws;
  unsigned short* Wh = (unsigned short*)ws;
  unsigned short* Wl = (unsigned short*)(ws + 1048576);
  unsigned int* cv = (unsigned int*)(ws + 2621440);
  unsigned int* d20g = (unsigned int*)(ws + 23592960);
  unsigned short* Ah = (unsigned short*)(ws + 2621440);
  unsigned short* Al = (unsigned short*)(ws + 36175872);
  float* partials = (float*)(ws + 69730304);

  knn_chunk_kernel<<<BB * 16 * 8, 128, 0, stream>>>(x, cv);
  knn_d20_kernel<<<ROW_G / 64, 64, 0, stream>>>(cv, d20g);
  knn_collect_kernel<<<ROW_G / 4, 256, 0, stream>>>(x, d20g, idx_ws);
  edgeconv_kernel<<<ROW_G / 4, 256, 0, stream>>>(x, idx_ws, W0, b0, Ah, Al);
  pool_mlp_kernel<64, 64, 16><<<ROW_G / 16, 256, 0, stream>>>(Ah, Al, idx_ws, W1, b1, 0, 64);
  pool_mlp_kernel<64, 128, 8><<<ROW_G / 8, 256, 0, stream>>>(Ah, Al, idx_ws, W2, b2, 64, 128);
  pool_mlp_kernel<128, 256, 8><<<ROW_G / 8, 256, 0, stream>>>(Ah, Al, idx_ws, W3, b3, 128, 256);
  wsplit_kernel<<<512, 256, 0, stream>>>(Wf, Wh, Wl);
  final_gemm_mfma<<<dim3(8, 16, BB), 256, 0, stream>>>(Ah, Al, Wh, Wl, partials);
  final_reduce_kernel<<<BB * 1024 / 256, 256, 0, stream>>>(partials, bf, out);
}

// Round 7
// 517.267 us; speedup vs baseline: 2.2061x; 1.0327x over previous
//
#include <hip/hip_runtime.h>

#define K_NN 20
#define NEG_INF (-__builtin_inff())

constexpr int BB   = 16;
constexpr int NN   = 2048;
constexpr int CATC = 512;                 // concat feature width
constexpr int ROW_G = BB * NN;            // 32768 points total

typedef short bf16x8 __attribute__((ext_vector_type(8)));   // 8 bf16 = 4 VGPR
typedef float f32x4  __attribute__((ext_vector_type(4)));

// ---------------- bf16 split helpers (hi = rn(a), lo = rn(a - hi)) ----------
__device__ __forceinline__ unsigned short f2bf_rn(float f) {
  unsigned int u = __float_as_uint(f);
  unsigned int r = u + 0x7FFFu + ((u >> 16) & 1u);
  return (unsigned short)(r >> 16);
}
__device__ __forceinline__ float bf2f(unsigned short h) {
  return __uint_as_float((unsigned int)h << 16);
}
__device__ __forceinline__ void split_store(float v, unsigned short* ph, unsigned short* pl) {
  const unsigned short h = f2bf_rn(v);
  *ph = h;
  *pl = f2bf_rn(v - bf2f(h));
}
__device__ __forceinline__ float join_hl(unsigned short h, unsigned short l) {
  return bf2f(h) + bf2f(l);
}

__device__ __forceinline__ int mbcnt(unsigned long long mask) {   // popc(mask & lanes_below)
  return __builtin_amdgcn_mbcnt_hi((unsigned int)(mask >> 32),
         __builtin_amdgcn_mbcnt_lo((unsigned int)mask, 0));
}

// ---------------------------------------------------------------------------
// Branch-free u32 top-20 VALUE network (desc, duplicates kept).
// ---------------------------------------------------------------------------
#define DECL_VALS(INIT) \
  unsigned int v0=INIT,v1=INIT,v2=INIT,v3=INIT,v4=INIT,v5=INIT,v6=INIT,v7=INIT, \
               v8=INIT,v9=INIT,v10=INIT,v11=INIT,v12=INIT,v13=INIT,v14=INIT,    \
               v15=INIT,v16=INIT,v17=INIT,v18=INIT,v19=INIT;

#define INSERT_VAL(x) do {                         \
    v19 = min(v18, max(v19, (x)));                 \
    v18 = min(v17, max(v18, (x)));                 \
    v17 = min(v16, max(v17, (x)));                 \
    v16 = min(v15, max(v16, (x)));                 \
    v15 = min(v14, max(v15, (x)));                 \
    v14 = min(v13, max(v14, (x)));                 \
    v13 = min(v12, max(v13, (x)));                 \
    v12 = min(v11, max(v12, (x)));                 \
    v11 = min(v10, max(v11, (x)));                 \
    v10 = min(v9,  max(v10, (x)));                 \
    v9  = min(v8,  max(v9,  (x)));                 \
    v8  = min(v7,  max(v8,  (x)));                 \
    v7  = min(v6,  max(v7,  (x)));                 \
    v6  = min(v5,  max(v6,  (x)));                 \
    v5  = min(v4,  max(v5,  (x)));                 \
    v4  = min(v3,  max(v4,  (x)));                 \
    v3  = min(v2,  max(v3,  (x)));                 \
    v2  = min(v1,  max(v2,  (x)));                 \
    v1  = min(v0,  max(v1,  (x)));                 \
    v0  = max(v0, (x));                            \
  } while (0)

__device__ __forceinline__ unsigned int sortable(float d) {
  unsigned int ub = __float_as_uint(d);
  return (ub & 0x80000000u) ? ~ub : (ub | 0x80000000u);
}

// ---------------------------------------------------------------------------
// kNN stage 1: per (batch, row-tile 128, candidate-chunk 256) top-20 values.
// ---------------------------------------------------------------------------
__global__ __launch_bounds__(128) void knn_chunk_kernel(const float* __restrict__ x,
                                                        unsigned int* __restrict__ cv) {
  __shared__ float4 cand[256];           // {x, y, z, sq} per candidate
  const int bid = blockIdx.x;
  const int ch = bid & 7;          // candidate chunk (8 x 256)
  const int rt = (bid >> 3) & 15;  // row tile (16 x 128)
  const int b  = bid >> 7;         // batch
  const float* xb = x + (size_t)b * NN * 3;

  for (int i = threadIdx.x; i < 256; i += 128) {
    const int m = ch * 256 + i;
    const float px = xb[m*3+0], py = xb[m*3+1], pz = xb[m*3+2];
    cand[i] = make_float4(px, py, pz, fmaf(pz, pz, fmaf(py, py, px*px)));
  }
  __syncthreads();

  const int n = rt * 128 + threadIdx.x;
  const float cx = xb[n*3+0], cy = xb[n*3+1], cz = xb[n*3+2];
  const float csq = fmaf(cz, cz, fmaf(cy, cy, cx*cx));

  DECL_VALS(0u)

#pragma unroll 4
  for (int i = 0; i < 256; ++i) {
    const float4 c = cand[i];
    const float inner = fmaf(cz, c.z, fmaf(cy, c.y, cx*c.x));
    const float d = 2.0f * inner - csq - c.w;      // same op order as reference
    const unsigned int u = sortable(d);
    INSERT_VAL(u);
  }

  const int rowg = b * NN + n;
#define STORE_VAL(i) cv[(size_t)(ch*K_NN + i) * ROW_G + rowg] = v##i;
  STORE_VAL(0) STORE_VAL(1) STORE_VAL(2) STORE_VAL(3) STORE_VAL(4)
  STORE_VAL(5) STORE_VAL(6) STORE_VAL(7) STORE_VAL(8) STORE_VAL(9)
  STORE_VAL(10) STORE_VAL(11) STORE_VAL(12) STORE_VAL(13) STORE_VAL(14)
  STORE_VAL(15) STORE_VAL(16) STORE_VAL(17) STORE_VAL(18) STORE_VAL(19)
#undef STORE_VAL
}

// ---------------------------------------------------------------------------
// kNN stage 2a: merge 8 chunk value-lists -> d20 (20th-largest) per row.
// ---------------------------------------------------------------------------
__global__ __launch_bounds__(64) void knn_d20_kernel(const unsigned int* __restrict__ cv,
                                                     unsigned int* __restrict__ d20g) {
  const int r = blockIdx.x * 64 + threadIdx.x;
#define LOAD_VAL(i) unsigned int v##i = cv[(size_t)i * ROW_G + r];
  LOAD_VAL(0) LOAD_VAL(1) LOAD_VAL(2) LOAD_VAL(3) LOAD_VAL(4)
  LOAD_VAL(5) LOAD_VAL(6) LOAD_VAL(7) LOAD_VAL(8) LOAD_VAL(9)
  LOAD_VAL(10) LOAD_VAL(11) LOAD_VAL(12) LOAD_VAL(13) LOAD_VAL(14)
  LOAD_VAL(15) LOAD_VAL(16) LOAD_VAL(17) LOAD_VAL(18) LOAD_VAL(19)
#undef LOAD_VAL
#pragma unroll 4
  for (int i = K_NN; i < 8 * K_NN; ++i)
    INSERT_VAL(cv[(size_t)i * ROW_G + r]);
  d20g[r] = v19;
}

// ---------------------------------------------------------------------------
// kNN stage 2b: ONE WAVE PER ROW. Rescan 2048 candidates (64/iter), compact
// members (dist > d20, <=19 of them) via ballot; ties (== d20) appended in
// ascending index order (k-major x lane order) -> exact top_k membership.
// ---------------------------------------------------------------------------
__global__ __launch_bounds__(256) void knn_collect_kernel(const float* __restrict__ x,
    const unsigned int* __restrict__ d20g, int* __restrict__ idx_out) {
  __shared__ float4 cand[NN];            // 32 KB, one batch
  __shared__ int tie[4][K_NN];
  const int w = threadIdx.x >> 6, lane = threadIdx.x & 63;
  const int r = blockIdx.x * 4 + w;      // 4 consecutive rows = same batch
  const int b = r >> 11;
  const float* xb = x + (size_t)b * NN * 3;

  for (int i = threadIdx.x; i < NN; i += 256) {
    const float px = xb[i*3+0], py = xb[i*3+1], pz = xb[i*3+2];
    cand[i] = make_float4(px, py, pz, fmaf(pz, pz, fmaf(py, py, px*px)));
  }
  __syncthreads();

  const int n = r & (NN - 1);
  const float4 ctr = cand[n];            // ctr.w == csq, bit-identical to stage 1
  const unsigned int d20 = d20g[r];
  int* op = idx_out + (size_t)r * K_NN;
  int cg = 0, ce = 0;

#pragma unroll 4
  for (int k = 0; k < NN / 64; ++k) {
    const int i = k * 64 + lane;
    const float4 c = cand[i];
    const float inner = fmaf(ctr.z, c.z, fmaf(ctr.y, c.y, ctr.x*c.x));
    const float d = 2.0f * inner - ctr.w - c.w;    // bit-identical to stage 1
    const unsigned int u = sortable(d);
    const unsigned long long mb = __ballot(u > d20);
    if (u > d20) op[cg + mbcnt(mb)] = i;
    cg += __popcll(mb);
    const unsigned long long tb = __ballot(u == d20);
    if (tb) {
      if (u == d20) {
        const int pos = ce + mbcnt(tb);
        if (pos < K_NN) tie[w][pos] = i;           // capped: only need <=20
      }
      ce += __popcll(tb);
    }
  }
  if (lane == 0)
    for (int j = 0; cg < K_NN; ++j, ++cg) op[cg] = tie[w][j];
}

// ---------------------------------------------------------------------------
// EdgeConv -> split bf16 planes Ah/Al cols [0,64)
// ---------------------------------------------------------------------------
__global__ __launch_bounds__(256) void edgeconv_kernel(const float* __restrict__ x,
    const int* __restrict__ idx, const float* __restrict__ W0,
    const float* __restrict__ b0, unsigned short* __restrict__ Ahg,
    unsigned short* __restrict__ Alg) {
  const int o  = threadIdx.x & 63;
  const int pt = blockIdx.x * 4 + (threadIdx.x >> 6);
  const int b  = pt >> 11, n = pt & (NN - 1);
  const float* xb = x + (size_t)b * NN * 3;

  const float w0 = W0[o*6+0], w1 = W0[o*6+1], w2 = W0[o*6+2];
  const float w3 = W0[o*6+3], w4 = W0[o*6+4], w5 = W0[o*6+5];
  const float bias = b0[o];
  const float cx = xb[n*3+0], cy = xb[n*3+1], cz = xb[n*3+2];

  const int* ip = idx + (size_t)pt * K_NN;
  float px = 0.f, py = 0.f, pz = 0.f;
  if (o < K_NN) { const int m = ip[o]; px = xb[m*3+0]; py = xb[m*3+1]; pz = xb[m*3+2]; }

  float best = NEG_INF;
#pragma unroll
  for (int k = 0; k < K_NN; ++k) {
    const float ax = __shfl(px, k, 64), ay = __shfl(py, k, 64), az = __shfl(pz, k, 64);
    float h = w0 * (ax - cx);
    h = fmaf(w1, ay - cy, h);
    h = fmaf(w2, az - cz, h);
    h = fmaf(w3, cx, h);
    h = fmaf(w4, cy, h);
    h = fmaf(w5, cz, h);
    h += bias;
    h = (h > 0.f) ? h : 0.2f * h;
    best = fmaxf(best, h);
  }
  split_store(best, &Ahg[(size_t)pt * CATC + o], &Alg[(size_t)pt * CATC + o]);
}

// ---------------------------------------------------------------------------
// pool (max over kNN graph, reading split h+l) + 1x1 conv + act -> split store
// ---------------------------------------------------------------------------
template<int CIN, int COUT, int PTS>
__global__ __launch_bounds__(256) void pool_mlp_kernel(
    unsigned short* __restrict__ Ahg, unsigned short* __restrict__ Alg,
    const int* __restrict__ idx, const float* __restrict__ W,
    const float* __restrict__ bias, int coff_in, int coff_out) {
  __shared__ float pooled[PTS][CIN];
  __shared__ int sidx[PTS][K_NN];
  const int pt0 = blockIdx.x * PTS;

  for (int t = threadIdx.x; t < PTS * K_NN; t += 256)
    sidx[t / K_NN][t % K_NN] = idx[(size_t)pt0 * K_NN + t];
  __syncthreads();

  for (int t = threadIdx.x; t < PTS * CIN; t += 256) {
    const int p = t / CIN, c = t % CIN;
    const int bq = (pt0 + p) >> 11;
    const size_t base = (size_t)bq * NN * CATC + coff_in + c;
    float mv = NEG_INF;
#pragma unroll
    for (int k = 0; k < K_NN; ++k) {
      const size_t a = base + (size_t)sidx[p][k] * CATC;
      mv = fmaxf(mv, join_hl(Ahg[a], Alg[a]));
    }
    pooled[p][c] = mv;
  }
  __syncthreads();

  for (int t = threadIdx.x; t < PTS * COUT; t += 256) {
    const int p = t / COUT, o = t % COUT;
    const float4* pp = (const float4*)&pooled[p][0];
    const float4* wp = (const float4*)(W + (size_t)o * CIN);
    float acc = 0.f;
#pragma unroll
    for (int c4 = 0; c4 < CIN / 4; ++c4) {
      const float4 pv = pp[c4], wv = wp[c4];
      acc = fmaf(pv.x, wv.x, acc);
      acc = fmaf(pv.y, wv.y, acc);
      acc = fmaf(pv.z, wv.z, acc);
      acc = fmaf(pv.w, wv.w, acc);
    }
    float h = acc + bias[o];
    h = (h > 0.f) ? h : 0.2f * h;
    const size_t a = (size_t)(pt0 + p) * CATC + coff_out + o;
    split_store(h, &Ahg[a], &Alg[a]);
  }
}

// ---------------------------------------------------------------------------
// Split Wf (1024x512 f32) -> Wh, Wl bf16
// ---------------------------------------------------------------------------
__global__ __launch_bounds__(256) void wsplit_kernel(const float* __restrict__ Wf,
    unsigned short* __restrict__ Wh, unsigned short* __restrict__ Wl) {
  const int t = blockIdx.x * 256 + threadIdx.x;   // 131072 float4 groups
  const float4 v = ((const float4*)Wf)[t];
  ushort4 h4, l4;
  h4.x = f2bf_rn(v.x); l4.x = f2bf_rn(v.x - bf2f(h4.x));
  h4.y = f2bf_rn(v.y); l4.y = f2bf_rn(v.y - bf2f(h4.y));
  h4.z = f2bf_rn(v.z); l4.z = f2bf_rn(v.z - bf2f(h4.z));
  h4.w = f2bf_rn(v.w); l4.w = f2bf_rn(v.w - bf2f(h4.w));
  ((ushort4*)Wh)[t] = h4;
  ((ushort4*)Wl)[t] = l4;
}

// ---------------------------------------------------------------------------
// Final GEMM via bf16x3 MFMA: C = A.Wf^T, running max over rows -> partials.
// Round 6 changes vs round 5:
//  - reg-staged PREFETCH: tile kt+1's 8 global loads issue right after the
//    LDS writes of kt -> latency hides under frag reads + 48 MFMAs (T14).
//  - XCD-panel swizzle (T1): decode (ot,chunk,b) from dispatch-linear L so
//    the 8 ot-blocks sharing an A-panel land on ONE XCD -> panel fetched
//    into L2 once instead of 8x.
//  - smax aliased into AhL -> LDS 41984->40960 B -> 4 blocks/CU.
// ---------------------------------------------------------------------------
__global__ __launch_bounds__(256) void final_gemm_mfma(
    const unsigned short* __restrict__ Ahg, const unsigned short* __restrict__ Alg,
    const unsigned short* __restrict__ Whg, const unsigned short* __restrict__ Wlg,
    float* __restrict__ partials) {
  __shared__ __align__(16) unsigned short AhL[128][40];
  __shared__ __align__(16) unsigned short AlL[128][40];
  __shared__ __align__(16) unsigned short WhL[128][40];
  __shared__ __align__(16) unsigned short WlL[128][40];

  // XCD-aware work decode: consecutive dispatch ids round-robin across the 8
  // XCDs; make each XCD process whole A-panels (all 8 ot's back-to-back).
  const int L     = blockIdx.x + (blockIdx.y << 3) + (blockIdx.z << 7);  // 0..2047
  const int xcd   = L & 7;
  const int q     = L >> 3;        // 0..255
  const int ot    = q & 7;         // col tile, varies fastest within an XCD
  const int s     = q >> 3;        // 0..31 panel slot on this XCD
  const int p     = (s << 3) | xcd;  // panel 0..255
  const int chunk = p & 15;
  const int b     = p >> 4;

  const int tid   = threadIdx.x;
  const int lane  = tid & 63;
  const int w     = tid >> 6;      // wave 0..3
  const int wr    = w >> 1;        // row half (64)
  const int wc    = w & 1;         // col half (64)
  const int fr    = lane & 15;     // fragment row/col within 16
  const int kg    = lane >> 4;     // k-group 0..3

  const int srow = tid >> 1;
  const int shalf = (tid & 1) * 16;
  const size_t arow = ((size_t)(b * NN) + (size_t)chunk * 128 + srow) * CATC;
  const size_t wrow = ((size_t)ot * 128 + srow) * CATC;

  f32x4 acc[4][4];
#pragma unroll
  for (int i = 0; i < 4; ++i)
#pragma unroll
    for (int j = 0; j < 4; ++j) acc[i][j] = (f32x4){0.f, 0.f, 0.f, 0.f};

  // prologue: load tile 0 into named staging regs
  uint4 ra0 = *(const uint4*)(Ahg + arow + shalf);
  uint4 ra1 = *(const uint4*)(Ahg + arow + shalf + 8);
  uint4 ra2 = *(const uint4*)(Alg + arow + shalf);
  uint4 ra3 = *(const uint4*)(Alg + arow + shalf + 8);
  uint4 rw0 = *(const uint4*)(Whg + wrow + shalf);
  uint4 rw1 = *(const uint4*)(Whg + wrow + shalf + 8);
  uint4 rw2 = *(const uint4*)(Wlg + wrow + shalf);
  uint4 rw3 = *(const uint4*)(Wlg + wrow + shalf + 8);

  for (int kt = 0; kt < 16; ++kt) {
    __syncthreads();   // prior iteration's frag reads complete
    *(uint4*)&AhL[srow][shalf]     = ra0;
    *(uint4*)&AhL[srow][shalf + 8] = ra1;
    *(uint4*)&AlL[srow][shalf]     = ra2;
    *(uint4*)&AlL[srow][shalf + 8] = ra3;
    *(uint4*)&WhL[srow][shalf]     = rw0;
    *(uint4*)&WhL[srow][shalf + 8] = rw1;
    *(uint4*)&WlL[srow][shalf]     = rw2;
    *(uint4*)&WlL[srow][shalf + 8] = rw3;
    if (kt < 15) {     // prefetch next tile; latency hides under MFMA phase
      const int k0 = (kt + 1) * 32;
      ra0 = *(const uint4*)(Ahg + arow + k0 + shalf);
      ra1 = *(const uint4*)(Ahg + arow + k0 + shalf + 8);
      ra2 = *(const uint4*)(Alg + arow + k0 + shalf);
      ra3 = *(const uint4*)(Alg + arow + k0 + shalf + 8);
      rw0 = *(const uint4*)(Whg + wrow + k0 + shalf);
      rw1 = *(const uint4*)(Whg + wrow + k0 + shalf + 8);
      rw2 = *(const uint4*)(Wlg + wrow + k0 + shalf);
      rw3 = *(const uint4*)(Wlg + wrow + k0 + shalf + 8);
    }
    __syncthreads();

    bf16x8 ahf[4], alf[4], whf[4], wlf[4];
#pragma unroll
    for (int i = 0; i < 4; ++i) {
      ahf[i] = *(const bf16x8*)&AhL[wr * 64 + i * 16 + fr][kg * 8];
      alf[i] = *(const bf16x8*)&AlL[wr * 64 + i * 16 + fr][kg * 8];
    }
#pragma unroll
    for (int j = 0; j < 4; ++j) {
      whf[j] = *(const bf16x8*)&WhL[wc * 64 + j * 16 + fr][kg * 8];
      wlf[j] = *(const bf16x8*)&WlL[wc * 64 + j * 16 + fr][kg * 8];
    }

#pragma unroll
    for (int i = 0; i < 4; ++i)
#pragma unroll
      for (int j = 0; j < 4; ++j) {
        acc[i][j] = __builtin_amdgcn_mfma_f32_16x16x32_bf16(ahf[i], whf[j], acc[i][j], 0, 0, 0);
        acc[i][j] = __builtin_amdgcn_mfma_f32_16x16x32_bf16(ahf[i], wlf[j], acc[i][j], 0, 0, 0);
        acc[i][j] = __builtin_amdgcn_mfma_f32_16x16x32_bf16(alf[i], whf[j], acc[i][j], 0, 0, 0);
      }
  }

  // ---- epilogue: max over the wave's 64 rows per output col ----
  __syncthreads();                       // all LDS frag reads done
  float* smax = (float*)&AhL[0][0];      // reuse AhL as smax[2][128]
#pragma unroll
  for (int j = 0; j < 4; ++j) {
    float mj = NEG_INF;
#pragma unroll
    for (int i = 0; i < 4; ++i) {
      mj = fmaxf(mj, fmaxf(fmaxf(acc[i][j][0], acc[i][j][1]),
                           fmaxf(acc[i][j][2], acc[i][j][3])));
    }
    mj = fmaxf(mj, __shfl_xor(mj, 16, 64));
    mj = fmaxf(mj, __shfl_xor(mj, 32, 64));
    if (lane < 16) smax[wr * 128 + wc * 64 + j * 16 + fr] = mj;
  }
  __syncthreads();
  if (tid < 128) {
    const float m = fmaxf(smax[tid], smax[128 + tid]);
    partials[((size_t)(b * 16 + chunk)) * 1024 + (size_t)ot * 128 + tid] = m;
  }
}

__global__ __launch_bounds__(256) void final_reduce_kernel(const float* __restrict__ partials,
    const float* __restrict__ bf, float* __restrict__ out) {
  const int t = blockIdx.x * 256 + threadIdx.x;   // 16384
  const int b = t >> 10, o = t & 1023;
  float m = NEG_INF;
#pragma unroll
  for (int c = 0; c < 16; ++c)
    m = fmaxf(m, partials[((size_t)(b * 16 + c)) * 1024 + o]);
  float h = m + bf[o];
  out[t] = (h > 0.f) ? h : 0.2f * h;   // act(max+b) == max(act(.+b)) (monotone)
}

// ---------------------------------------------------------------------------
extern "C" void kernel_launch(void* const* d_in, const int* in_sizes, int n_in,
                              void* d_out, int out_size, void* d_ws, size_t ws_size,
                              hipStream_t stream) {
  (void)in_sizes; (void)n_in; (void)out_size; (void)ws_size;
  const float* x  = (const float*)d_in[0];
  const float* W0 = (const float*)d_in[1];
  const float* b0 = (const float*)d_in[2];
  const float* W1 = (const float*)d_in[3];
  const float* b1 = (const float*)d_in[4];
  const float* W2 = (const float*)d_in[5];
  const float* b2 = (const float*)d_in[6];
  const float* W3 = (const float*)d_in[7];
  const float* b3 = (const float*)d_in[8];
  const float* Wf = (const float*)d_in[9];
  const float* bf = (const float*)d_in[10];
  float* out = (float*)d_out;

  // ws layout (bytes), total 70,778,880:
  //   [0, 2621440)           : idx (int 32768x20) -- dead after pool3;
  //                            Wh [0,1MB) + Wl [1MB,2MB) alias (wsplit after pool3)
  //   [2621440, 23592960)    : cv (u32 160x32768) -- dead after d20, aliased under Ah
  //   [23592960, 23724032)   : d20 (u32 32768)    -- dead after collect, under Ah
  //   [2621440, 36175872)    : Ah bf16[32768][512] (written from edgeconv onward)
  //   [36175872, 69730304)   : Al bf16[32768][512]
  //   [69730304, 70778880)   : partials (float 16*16*1024)
  char* ws = (char*)d_ws;
  int* idx_ws = (int*)ws;
  unsigned short* Wh = (unsigned short*)ws;
  unsigned short* Wl = (unsigned short*)(ws + 1048576);
  unsigned int* cv = (unsigned int*)(ws + 2621440);
  unsigned int* d20g = (unsigned int*)(ws + 23592960);
  unsigned short* Ah = (unsigned short*)(ws + 2621440);
  unsigned short* Al = (unsigned short*)(ws + 36175872);
  float* partials = (float*)(ws + 69730304);

  knn_chunk_kernel<<<BB * 16 * 8, 128, 0, stream>>>(x, cv);
  knn_d20_kernel<<<ROW_G / 64, 64, 0, stream>>>(cv, d20g);
  knn_collect_kernel<<<ROW_G / 4, 256, 0, stream>>>(x, d20g, idx_ws);
  edgeconv_kernel<<<ROW_G / 4, 256, 0, stream>>>(x, idx_ws, W0, b0, Ah, Al);
  pool_mlp_kernel<64, 64, 16><<<ROW_G / 16, 256, 0, stream>>>(Ah, Al, idx_ws, W1, b1, 0, 64);
  pool_mlp_kernel<64, 128, 8><<<ROW_G / 8, 256, 0, stream>>>(Ah, Al, idx_ws, W2, b2, 64, 128);
  pool_mlp_kernel<128, 256, 8><<<ROW_G / 8, 256, 0, stream>>>(Ah, Al, idx_ws, W3, b3, 128, 256);
  wsplit_kernel<<<512, 256, 0, stream>>>(Wf, Wh, Wl);
  final_gemm_mfma<<<dim3(8, 16, BB), 256, 0, stream>>>(Ah, Al, Wh, Wl, partials);
  final_reduce_kernel<<<BB * 1024 / 256, 256, 0, stream>>>(partials, bf, out);
}